// Round 10
// baseline (717.219 us; speedup 1.0000x reference)
//
#include <hip/hip_runtime.h>
#include <hip/hip_bf16.h>
#include <math.h>

#define N_TOK 8192
#define DIM   1024
#define HID   2048
#define NE    8
#define NT1   16     // DIM/64 K-tiles (ffn1)
#define NT2   32     // HID/64 K-tiles (ffn2)
#define NB1   16     // HID/128 panels (ffn1)
#define NB2   4      // DIM/256 panels (ffn2)
#define PANEL1_SH ((size_t)(128 * 256 * 8))   // shorts per ffn1 [W1|W2] panel (512KB)
#define PANEL3_SH ((size_t)(256 * 256 * 8))   // shorts per w3 256-col panel (1MB)
#define HBLK_SH   ((size_t)(256 * 128 * 8))   // shorts per 128-row Hsw block (512KB)

typedef __attribute__((ext_vector_type(8))) short short8;
typedef __attribute__((ext_vector_type(4))) float f32x4;
typedef unsigned short us;

__device__ __forceinline__ us f2bf(float f) {
    unsigned int u = __builtin_bit_cast(unsigned int, f);
    unsigned int r = (u + 0x7fffu + ((u >> 16) & 1u)) >> 16;   // RNE
    return (us)r;
}

__device__ __forceinline__ void gl_lds16(const us* g, us* l) {
    __builtin_amdgcn_global_load_lds(
        (const __attribute__((address_space(1))) void*)g,
        (__attribute__((address_space(3))) void*)l, 16, 0, 0);
}

#define VMW4 asm volatile("s_waitcnt vmcnt(4)" ::: "memory")
#define VMW0 asm volatile("s_waitcnt vmcnt(0)" ::: "memory")
#define BARM asm volatile("s_barrier" ::: "memory")
#define PRIO1 __builtin_amdgcn_s_setprio(1)
#define PRIO0 __builtin_amdgcn_s_setprio(0)

// ---------------- gating (+ fused x->bf16) ----------------
__global__ __launch_bounds__(256) void gate_kernel(
    const float* __restrict__ x, const float* __restrict__ gw, const float* __restrict__ gb,
    float* __restrict__ usage, int* __restrict__ counts,
    int* __restrict__ lists, float* __restrict__ wts,
    us* __restrict__ xb)
{
    const int lane = threadIdx.x & 63;
    const int tok = blockIdx.x * 4 + (threadIdx.x >> 6);

    __shared__ float su[NE];
    if (threadIdx.x < NE) su[threadIdx.x] = 0.f;
    __syncthreads();

    float acc[NE];
#pragma unroll
    for (int e = 0; e < NE; e++) acc[e] = 0.f;

    const float* xr = x + (size_t)tok * DIM;
    us* xbr = xb + (size_t)tok * DIM;
    for (int d = lane; d < DIM; d += 64) {
        float xv = xr[d];
        xbr[d] = f2bf(xv);
        const float4* g4 = (const float4*)(gw + (size_t)d * NE);
        float4 ga = g4[0], gc = g4[1];
        acc[0] = fmaf(xv, ga.x, acc[0]);
        acc[1] = fmaf(xv, ga.y, acc[1]);
        acc[2] = fmaf(xv, ga.z, acc[2]);
        acc[3] = fmaf(xv, ga.w, acc[3]);
        acc[4] = fmaf(xv, gc.x, acc[4]);
        acc[5] = fmaf(xv, gc.y, acc[5]);
        acc[6] = fmaf(xv, gc.z, acc[6]);
        acc[7] = fmaf(xv, gc.w, acc[7]);
    }
#pragma unroll
    for (int e = 0; e < NE; e++) {
#pragma unroll
        for (int off = 32; off > 0; off >>= 1)
            acc[e] += __shfl_xor(acc[e], off);
    }

    if (lane == 0) {
        float lg[NE], p[NE];
        float mx = -1e30f;
#pragma unroll
        for (int e = 0; e < NE; e++) { lg[e] = acc[e] + gb[e]; mx = fmaxf(mx, lg[e]); }
        float s = 0.f;
#pragma unroll
        for (int e = 0; e < NE; e++) { p[e] = __expf(lg[e] - mx); s += p[e]; }
        float inv = 1.f / s;
#pragma unroll
        for (int e = 0; e < NE; e++) p[e] *= inv;
#pragma unroll
        for (int e = 0; e < NE; e++) atomicAdd(&su[e], p[e]);

        int e1 = 0; float v1 = p[0];
#pragma unroll
        for (int e = 1; e < NE; e++) if (p[e] > v1) { v1 = p[e]; e1 = e; }
        int e2 = -1; float v2 = -1e30f;
#pragma unroll
        for (int e = 0; e < NE; e++) if (e != e1 && p[e] > v2) { v2 = p[e]; e2 = e; }

        int pos1 = atomicAdd(&counts[e1], 1);
        lists[e1 * N_TOK + pos1] = tok * 2 + 0;
        wts[e1 * N_TOK + pos1] = v1;
        int pos2 = atomicAdd(&counts[e2], 1);
        lists[e2 * N_TOK + pos2] = tok * 2 + 1;
        wts[e2 * N_TOK + pos2] = v2;
    }
    __syncthreads();
    if (threadIdx.x < NE) atomicAdd(&usage[threadIdx.x], su[threadIdx.x]);
}

__global__ void loss_kernel(const float* __restrict__ usage, float* __restrict__ out_loss)
{
    if (threadIdx.x == 0) {
        float l = 0.f;
        for (int e = 0; e < NE; e++) {
            float u = usage[e] / (float)N_TOK;
            l += u * logf(u + 1e-9f);
        }
        *out_loss = l;
    }
}

// base[e] = 128-aligned prefix of counts
__global__ void prefix_kernel(const int* __restrict__ counts, int* __restrict__ base)
{
    if (threadIdx.x == 0) {
        int b = 0;
        for (int e = 0; e < NE; e++) { base[e] = b; b += (counts[e] + 127) & ~127; }
    }
}

// ---------------- w1,w2 -> [e][nbx16][g128][row256][8], rows = [W1 128 | W2 128] ----------------
__global__ __launch_bounds__(256) void wswz12_kernel(
    const float* __restrict__ w1, const float* __restrict__ w2, us* __restrict__ out)
{
    const int e = blockIdx.z, nbx = blockIdx.y, gs = blockIdx.x;   // gs 0..15
    us* op = out + ((size_t)e * NB1 + nbx) * PANEL1_SH + (size_t)gs * 8 * 256 * 8;
    const float* w1e = w1 + (size_t)e * DIM * HID;
    const float* w2e = w2 + (size_t)e * DIM * HID;
    const int t = threadIdx.x;
#pragma unroll
    for (int it = 0; it < 8; it++) {
        int idx = it * 256 + t;          // 0..2047 = g(8) x row(256)
        int g = idx >> 8, row = idx & 255;
        int col = nbx * 128 + (row & 127);
        const float* src = (row < 128 ? w1e : w2e) + (size_t)((gs * 8 + g) * 8) * HID + col;
        short8 v;
#pragma unroll
        for (int s = 0; s < 8; s++) v[s] = (short)f2bf(src[(size_t)s * HID]);
        *(short8*)(op + (size_t)idx * 8) = v;
    }
}

// ---------------- w3 -> [e][nbx4][g256][row256][8], row = col nbx*256+row ----------------
__global__ __launch_bounds__(256) void wswz3_kernel(
    const float* __restrict__ w3, us* __restrict__ out)
{
    const int e = blockIdx.z, nbx = blockIdx.y, gs = blockIdx.x;   // gs 0..31
    us* op = out + ((size_t)e * NB2 + nbx) * PANEL3_SH + (size_t)gs * 8 * 256 * 8;
    const float* w3e = w3 + (size_t)e * HID * DIM;
    const int t = threadIdx.x;
#pragma unroll
    for (int it = 0; it < 8; it++) {
        int idx = it * 256 + t;
        int g = idx >> 8, row = idx & 255;
        int col = nbx * 256 + row;
        const float* src = w3e + (size_t)((gs * 8 + g) * 8) * DIM + col;
        short8 v;
#pragma unroll
        for (int s = 0; s < 8; s++) v[s] = (short)f2bf(src[(size_t)s * DIM]);
        *(short8*)(op + (size_t)idx * 8) = v;
    }
}

// ---------------- pass A: Xg @ [W1|W2] -> swiglu -> Hsw ----------------
// BM=256, Bpanel=256([W1|W2]); BK=64; 8 waves 2Mx4N, per-wave 128x64.
__global__ __launch_bounds__(512, 2) void ffn1_mfma_kernel(
    const us* __restrict__ Xbf, const us* __restrict__ W12sw,
    const float* __restrict__ b1, const float* __restrict__ b2,
    const int* __restrict__ counts, const int* __restrict__ lists, const int* __restrict__ base,
    us* __restrict__ Hsw)
{
    const int e = blockIdx.z;
    const int cnt = counts[e];
    const int m0 = blockIdx.y * 256;
    if (m0 >= cnt) return;
    const int nbx = blockIdx.x;

    __shared__ __align__(16) unsigned char SM[133120];
    int* rowids = (int*)(SM + 132096);

    const int t = threadIdx.x;
    if (t < 256) {
        int idx = m0 + t;
        rowids[t] = (idx < cnt) ? lists[e * N_TOK + idx] : 0;   // clamp tail to a valid row
    }

    const int lane = t & 63, wv = t >> 6;
    const int wr = wv >> 2, wc = wv & 3;            // 2M x 4N
    const int Mw = wr * 128, Nw = wc * 64;
    const int fr = lane & 15, kc = lane >> 4;

    float bb[4];
    {
        const float* bsrc = (wc < 2) ? b1 : b2;
#pragma unroll
        for (int ni = 0; ni < 4; ni++)
            bb[ni] = bsrc[e * HID + nbx * 128 + (wc & 1) * 64 + ni * 16 + fr];
    }
    __syncthreads();   // rowids visible; vmcnt drained

    // DMA chunk assignment: thread covers chunks c0, c1=c0+64 of each 1024-chunk half
    const int c0 = (wv)*128 + lane;
    const int c1 = c0 + 64;
    const int r0 = c0 & 255, r1 = c1 & 255;
    const us* ApA = Xbf + (size_t)(rowids[r0] >> 1) * DIM + (c0 >> 8) * 8;
    const us* ApB = Xbf + (size_t)(rowids[r1] >> 1) * DIM + (c1 >> 8) * 8;
    const us* Wp = W12sw + ((size_t)e * NB1 + nbx) * PANEL1_SH;
    const int dbase = (wv)*128 * 8;                 // wave-uniform LDS short base

    f32x4 acc[8][4];
    const f32x4 fz = {0.f, 0.f, 0.f, 0.f};
#pragma unroll
    for (int i = 0; i < 8; i++)
#pragma unroll
        for (int j = 0; j < 4; j++) acc[i][j] = fz;

    #define ABUF(b) ((us*)(SM + (b)*32768))
    #define BBUF(b) ((us*)(SM + 65536 + (b)*32768))

    #define STAGE_A(b, tile, h) do {                                         \
        gl_lds16(ApA + (tile)*64 + (h)*32, ABUF(b) + ((h)*1024)*8 + dbase);  \
        gl_lds16(ApB + (tile)*64 + (h)*32, ABUF(b) + ((h)*1024 + 64)*8 + dbase); \
    } while (0)
    #define STAGE_B(b, tile, h) do {                                         \
        const us* s_ = Wp + ((size_t)(tile)*2048 + (h)*1024) * 8;            \
        gl_lds16(s_ + (size_t)c0 * 8, BBUF(b) + ((h)*1024)*8 + dbase);       \
        gl_lds16(s_ + (size_t)c1 * 8, BBUF(b) + ((h)*1024 + 64)*8 + dbase);  \
    } while (0)

    #define AF_READ(b, h) do {                                               \
        _Pragma("unroll")                                                    \
        for (int mi = 0; mi < 8; mi++)                                       \
            af[mi] = *(const short8*)(ABUF(b) + ((h)*1024 + kc*256 + Mw + mi*16 + fr)*8); \
    } while (0)
    #define BF_READ(b, h, nh) do {                                           \
        bf[0] = *(const short8*)(BBUF(b) + ((h)*1024 + kc*256 + Nw + (nh)*32 + fr)*8); \
        bf[1] = *(const short8*)(BBUF(b) + ((h)*1024 + kc*256 + Nw + (nh)*32 + 16 + fr)*8); \
    } while (0)
    #define CLUST(nh) do {                                                   \
        PRIO1;                                                               \
        _Pragma("unroll")                                                    \
        for (int ni = 0; ni < 2; ni++) {                                     \
            _Pragma("unroll")                                                \
            for (int mi = 0; mi < 8; mi++)                                   \
                acc[mi][(nh)*2 + ni] = __builtin_amdgcn_mfma_f32_16x16x32_bf16( \
                    af[mi], bf[ni], acc[mi][(nh)*2 + ni], 0, 0, 0);          \
        }                                                                    \
        PRIO0;                                                               \
    } while (0)

    short8 af[8], bf[2];

    STAGE_A(0, 0, 0); STAGE_B(0, 0, 0); STAGE_A(0, 0, 1); STAGE_B(0, 0, 1);
    VMW4; BARM;

    for (int tl = 0; tl < NT1; ++tl) {
        const int b = tl & 1, nb = b ^ 1;
        const bool more = (tl + 1 < NT1);
        // P0
        AF_READ(b, 0); BF_READ(b, 0, 0);
        if (more) STAGE_A(nb, tl + 1, 0);
        BARM; CLUST(0); BARM;
        // P1
        BF_READ(b, 0, 1);
        if (more) { STAGE_B(nb, tl + 1, 0); VMW4; } else { VMW0; }
        BARM; CLUST(1); BARM;
        // P2
        AF_READ(b, 1); BF_READ(b, 1, 0);
        if (more) STAGE_A(nb, tl + 1, 1);
        BARM; CLUST(0); BARM;
        // P3
        BF_READ(b, 1, 1);
        if (more) { STAGE_B(nb, tl + 1, 1); VMW4; }
        BARM; CLUST(1); BARM;
    }

    // ---- SwiGLU epilogue via LDS gate exchange ----
    float* G = (float*)SM;                      // [256][129] f32 = 132096 B
    const int padcnt = (cnt + 127) & ~127;
    if (wc >= 2) {
        const int cp = wc - 2;
#pragma unroll
        for (int ni = 0; ni < 4; ni++) {
            int c2 = cp * 64 + ni * 16 + fr;
#pragma unroll
            for (int mi = 0; mi < 8; mi++) {
#pragma unroll
                for (int j = 0; j < 4; j++) {
                    int m = mi * 16 + kc * 4 + j;
                    float g = 1.f / (1.f + __expf(-(acc[mi][ni][j] + bb[ni])));
                    G[(wr * 128 + c2) * 129 + m] = g;
                }
            }
        }
    }
    __syncthreads();   // full lgkmcnt drain: G writes visible to all waves
    if (wc < 2) {
#pragma unroll
        for (int ni = 0; ni < 4; ni++) {
            int c2 = wc * 64 + ni * 16 + fr;
            int ch = nbx * 128 + c2;
            size_t cb = (size_t)(ch >> 3) * 128 * 8 + (ch & 7);
#pragma unroll
            for (int mi = 0; mi < 8; mi++) {
#pragma unroll
                for (int j = 0; j < 4; j++) {
                    int m = mi * 16 + kc * 4 + j;
                    int rl = wr * 128 + m;
                    if (m0 + rl >= padcnt) continue;
                    float h = (acc[mi][ni][j] + bb[ni]) * G[(wr * 128 + c2) * 129 + m];
                    int R = base[e] + m0 + rl;
                    Hsw[(size_t)(R >> 7) * HBLK_SH + cb + (size_t)(R & 127) * 8] = f2bf(h);
                }
            }
        }
    }
    #undef STAGE_A
    #undef STAGE_B
}

// ---------------- pass B: Hsw @ w3 -> scaled atomicAdd into out ----------------
__global__ __launch_bounds__(512, 2) void ffn2_mfma_kernel(
    const us* __restrict__ Hsw, const us* __restrict__ W3sw, const float* __restrict__ b3,
    const int* __restrict__ counts, const int* __restrict__ lists, const float* __restrict__ wts,
    const int* __restrict__ base,
    float* __restrict__ out)
{
    const int e = blockIdx.z;
    const int cnt = counts[e];
    const int m0 = blockIdx.y * 256;
    if (m0 >= cnt) return;
    const int nbx = blockIdx.x;

    __shared__ __align__(16) unsigned char SM[133120];
    int* rowids = (int*)(SM + 131072);
    float* rowwt = (float*)(SM + 132096);

    const int t = threadIdx.x;
    if (t < 256) {
        int idx = m0 + t;
        if (idx < cnt) { rowids[t] = lists[e * N_TOK + idx]; rowwt[t] = wts[e * N_TOK + idx]; }
        else           { rowids[t] = -1; rowwt[t] = 0.f; }
    }

    const int lane = t & 63, wv = t >> 6;
    const int wr = wv >> 2, wc = wv & 3;
    const int Mw = wr * 128, Nw = wc * 64;
    const int fr = lane & 15, kc = lane >> 4;

    float bb3[4];
#pragma unroll
    for (int ni = 0; ni < 4; ni++)
        bb3[ni] = b3[e * DIM + nbx * 256 + wc * 64 + ni * 16 + fr];
    __syncthreads();

    const int c0 = (wv)*128 + lane;
    const int c1 = c0 + 64;
    const int r0 = c0 & 255, r1 = c1 & 255;
    const int blk0 = (base[e] + m0) >> 7;
    const us* HpA = Hsw + (size_t)(blk0 + (r0 >> 7)) * HBLK_SH + ((c0 >> 8) * 128 + (r0 & 127)) * 8;
    const us* HpB = Hsw + (size_t)(blk0 + (r1 >> 7)) * HBLK_SH + ((c1 >> 8) * 128 + (r1 & 127)) * 8;
    const us* Wp = W3sw + ((size_t)e * NB2 + nbx) * PANEL3_SH;
    const int dbase = (wv)*128 * 8;

    f32x4 acc[8][4];
    const f32x4 fz = {0.f, 0.f, 0.f, 0.f};
#pragma unroll
    for (int i = 0; i < 8; i++)
#pragma unroll
        for (int j = 0; j < 4; j++) acc[i][j] = fz;

    #define STAGE_A2(b, tile, h) do {                                            \
        gl_lds16(HpA + ((size_t)(tile)*1024 + (h)*512) * 8, ABUF(b) + ((h)*1024)*8 + dbase); \
        gl_lds16(HpB + ((size_t)(tile)*1024 + (h)*512) * 8, ABUF(b) + ((h)*1024 + 64)*8 + dbase); \
    } while (0)
    #define STAGE_B2(b, tile, h) do {                                            \
        const us* s_ = Wp + ((size_t)(tile)*2048 + (h)*1024) * 8;                \
        gl_lds16(s_ + (size_t)c0 * 8, BBUF(b) + ((h)*1024)*8 + dbase);           \
        gl_lds16(s_ + (size_t)c1 * 8, BBUF(b) + ((h)*1024 + 64)*8 + dbase);      \
    } while (0)

    short8 af[8], bf[2];

    STAGE_A2(0, 0, 0); STAGE_B2(0, 0, 0); STAGE_A2(0, 0, 1); STAGE_B2(0, 0, 1);
    VMW4; BARM;

    for (int tl = 0; tl < NT2; ++tl) {
        const int b = tl & 1, nb = b ^ 1;
        const bool more = (tl + 1 < NT2);
        AF_READ(b, 0); BF_READ(b, 0, 0);
        if (more) STAGE_A2(nb, tl + 1, 0);
        BARM; CLUST(0); BARM;
        BF_READ(b, 0, 1);
        if (more) { STAGE_B2(nb, tl + 1, 0); VMW4; } else { VMW0; }
        BARM; CLUST(1); BARM;
        AF_READ(b, 1); BF_READ(b, 1, 0);
        if (more) STAGE_A2(nb, tl + 1, 1);
        BARM; CLUST(0); BARM;
        BF_READ(b, 1, 1);
        if (more) { STAGE_B2(nb, tl + 1, 1); VMW4; }
        BARM; CLUST(1); BARM;
    }

#pragma unroll
    for (int ni = 0; ni < 4; ni++) {
        int col = nbx * 256 + wc * 64 + ni * 16 + fr;
#pragma unroll
        for (int mi = 0; mi < 8; mi++) {
#pragma unroll
            for (int j = 0; j < 4; j++) {
                int rl = wr * 128 + mi * 16 + kc * 4 + j;
                int rid = rowids[rl];
                if (rid < 0) continue;
                float v = (acc[mi][ni][j] + bb3[ni]) * rowwt[rl];
                atomicAdd(&out[(size_t)(rid >> 1) * DIM + col], v);
            }
        }
    }
}

extern "C" void kernel_launch(void* const* d_in, const int* in_sizes, int n_in,
                              void* d_out, int out_size, void* d_ws, size_t ws_size,
                              hipStream_t stream) {
    (void)in_sizes; (void)n_in; (void)out_size; (void)ws_size;
    const float* x      = (const float*)d_in[0];
    const float* gate_w = (const float*)d_in[1];
    const float* gate_b = (const float*)d_in[2];
    const float* w1     = (const float*)d_in[3];
    const float* b1     = (const float*)d_in[4];
    const float* w2     = (const float*)d_in[5];
    const float* b2     = (const float*)d_in[6];
    const float* w3     = (const float*)d_in[7];
    const float* b3     = (const float*)d_in[8];
    float* out = (float*)d_out;

    char* ws = (char*)d_ws;
    float* usage  = (float*)ws;                                   // @0, 32 B
    int*   counts = (int*)(ws + 32);                              // @32, 32 B
    int*   base   = (int*)(ws + 64);                              // @64, 64 B
    int*   lists  = (int*)(ws + 128);                             // 256 KB
    float* wts    = (float*)(ws + 128 + (size_t)NE * N_TOK * 4);  // 256 KB
    us* Hsw   = (us*)(ws + (1ull  << 20));                        // @1 MiB, <=68 MiB
    us* W12sw = (us*)(ws + (69ull << 20));                        // @69 MiB, 64 MiB
    us* W3sw  = W12sw;                                            // 32 MiB, reused after ffn1
    us* Xbf   = (us*)d_out;                                       // 16 MiB, pre-zeroing

    hipMemsetAsync(ws, 0, 128, stream);

    gate_kernel<<<N_TOK / 4, 256, 0, stream>>>(x, gate_w, gate_b, usage, counts, lists, wts, Xbf);
    prefix_kernel<<<1, 64, 0, stream>>>(counts, base);

    dim3 gW12(16, NB1, NE);
    wswz12_kernel<<<gW12, 256, 0, stream>>>(w1, w2, W12sw);

    dim3 gA(NB1, 64, NE);
    ffn1_mfma_kernel<<<gA, 512, 0, stream>>>(Xbf, W12sw, b1, b2, counts, lists, base, Hsw);

    hipMemsetAsync(d_out, 0, (size_t)N_TOK * DIM * sizeof(float), stream);
    loss_kernel<<<1, 64, 0, stream>>>(usage, out + (size_t)N_TOK * DIM);

    dim3 gW3(32, NB2, NE);
    wswz3_kernel<<<gW3, 256, 0, stream>>>(w3, W3sw);

    dim3 gB(NB2, 64, NE);
    ffn2_mfma_kernel<<<gB, 512, 0, stream>>>(Hsw, W3sw, b3, counts, lists, wts, base, out);
}

// Round 11
// 702.327 us; speedup vs baseline: 1.0212x; 1.0212x over previous
//
#include <hip/hip_runtime.h>
#include <hip/hip_bf16.h>
#include <math.h>

#define N_TOK 8192
#define DIM   1024
#define HID   2048
#define NE    8
#define NT1   16     // DIM/64 K-tiles (ffn1)
#define NT2   32     // HID/64 K-tiles (ffn2)
#define NB1   16     // HID/128 panels (ffn1)
#define NB2   4      // DIM/256 panels (ffn2)
#define PANEL1_SH ((size_t)(128 * 256 * 8))   // shorts per ffn1 [W1|W2] panel (512KB)
#define PANEL3_SH ((size_t)(256 * 256 * 8))   // shorts per w3 256-col panel (1MB)
#define HBLK_SH   ((size_t)(256 * 128 * 8))   // shorts per 128-row Hsw block (512KB)

typedef __attribute__((ext_vector_type(8))) short short8;
typedef __attribute__((ext_vector_type(4))) float f32x4;
typedef unsigned short us;

__device__ __forceinline__ us f2bf(float f) {
    unsigned int u = __builtin_bit_cast(unsigned int, f);
    unsigned int r = (u + 0x7fffu + ((u >> 16) & 1u)) >> 16;   // RNE
    return (us)r;
}

__device__ __forceinline__ void gl_lds16(const us* g, us* l) {
    __builtin_amdgcn_global_load_lds(
        (const __attribute__((address_space(1))) void*)g,
        (__attribute__((address_space(3))) void*)l, 16, 0, 0);
}

#define VMW4 asm volatile("s_waitcnt vmcnt(4)" ::: "memory")
#define VMW0 asm volatile("s_waitcnt vmcnt(0)" ::: "memory")
#define BARM asm volatile("s_barrier" ::: "memory")
#define PRIO1 __builtin_amdgcn_s_setprio(1)
#define PRIO0 __builtin_amdgcn_s_setprio(0)

// ---------------- gating (+ fused x->bf16) ----------------
__global__ __launch_bounds__(256) void gate_kernel(
    const float* __restrict__ x, const float* __restrict__ gw, const float* __restrict__ gb,
    float* __restrict__ usage, int* __restrict__ counts,
    int* __restrict__ lists, float* __restrict__ wts,
    us* __restrict__ xb)
{
    const int lane = threadIdx.x & 63;
    const int tok = blockIdx.x * 4 + (threadIdx.x >> 6);

    __shared__ float su[NE];
    if (threadIdx.x < NE) su[threadIdx.x] = 0.f;
    __syncthreads();

    float acc[NE];
#pragma unroll
    for (int e = 0; e < NE; e++) acc[e] = 0.f;

    const float* xr = x + (size_t)tok * DIM;
    us* xbr = xb + (size_t)tok * DIM;
    for (int d = lane; d < DIM; d += 64) {
        float xv = xr[d];
        xbr[d] = f2bf(xv);
        const float4* g4 = (const float4*)(gw + (size_t)d * NE);
        float4 ga = g4[0], gc = g4[1];
        acc[0] = fmaf(xv, ga.x, acc[0]);
        acc[1] = fmaf(xv, ga.y, acc[1]);
        acc[2] = fmaf(xv, ga.z, acc[2]);
        acc[3] = fmaf(xv, ga.w, acc[3]);
        acc[4] = fmaf(xv, gc.x, acc[4]);
        acc[5] = fmaf(xv, gc.y, acc[5]);
        acc[6] = fmaf(xv, gc.z, acc[6]);
        acc[7] = fmaf(xv, gc.w, acc[7]);
    }
#pragma unroll
    for (int e = 0; e < NE; e++) {
#pragma unroll
        for (int off = 32; off > 0; off >>= 1)
            acc[e] += __shfl_xor(acc[e], off);
    }

    if (lane == 0) {
        float lg[NE], p[NE];
        float mx = -1e30f;
#pragma unroll
        for (int e = 0; e < NE; e++) { lg[e] = acc[e] + gb[e]; mx = fmaxf(mx, lg[e]); }
        float s = 0.f;
#pragma unroll
        for (int e = 0; e < NE; e++) { p[e] = __expf(lg[e] - mx); s += p[e]; }
        float inv = 1.f / s;
#pragma unroll
        for (int e = 0; e < NE; e++) p[e] *= inv;
#pragma unroll
        for (int e = 0; e < NE; e++) atomicAdd(&su[e], p[e]);

        int e1 = 0; float v1 = p[0];
#pragma unroll
        for (int e = 1; e < NE; e++) if (p[e] > v1) { v1 = p[e]; e1 = e; }
        int e2 = -1; float v2 = -1e30f;
#pragma unroll
        for (int e = 0; e < NE; e++) if (e != e1 && p[e] > v2) { v2 = p[e]; e2 = e; }

        int pos1 = atomicAdd(&counts[e1], 1);
        lists[e1 * N_TOK + pos1] = tok * 2 + 0;
        wts[e1 * N_TOK + pos1] = v1;
        int pos2 = atomicAdd(&counts[e2], 1);
        lists[e2 * N_TOK + pos2] = tok * 2 + 1;
        wts[e2 * N_TOK + pos2] = v2;
    }
    __syncthreads();
    if (threadIdx.x < NE) atomicAdd(&usage[threadIdx.x], su[threadIdx.x]);
}

__global__ void loss_kernel(const float* __restrict__ usage, float* __restrict__ out_loss)
{
    if (threadIdx.x == 0) {
        float l = 0.f;
        for (int e = 0; e < NE; e++) {
            float u = usage[e] / (float)N_TOK;
            l += u * logf(u + 1e-9f);
        }
        *out_loss = l;
    }
}

// base[e] = 128-aligned prefix; base_exact[e] = exact prefix
__global__ void prefix_kernel(const int* __restrict__ counts,
                              int* __restrict__ base, int* __restrict__ base_exact)
{
    if (threadIdx.x == 0) {
        int b = 0, bx = 0;
        for (int e = 0; e < NE; e++) {
            base[e] = b;        b  += (counts[e] + 127) & ~127;
            base_exact[e] = bx; bx += counts[e];
        }
    }
}

// inv[rid] = global (exact) list position of routing entry rid
__global__ __launch_bounds__(256) void inv_kernel(
    const int* __restrict__ counts, const int* __restrict__ lists,
    const int* __restrict__ base_exact, int* __restrict__ inv)
{
    const int e = blockIdx.y;
    const int idx = blockIdx.x * 256 + threadIdx.x;
    if (idx < counts[e]) inv[lists[e * N_TOK + idx]] = base_exact[e] + idx;
}

// ---------------- w1,w2 -> [e][nbx16][g128][row256][8], rows = [W1 128 | W2 128] ----------------
__global__ __launch_bounds__(256) void wswz12_kernel(
    const float* __restrict__ w1, const float* __restrict__ w2, us* __restrict__ out)
{
    const int e = blockIdx.z, nbx = blockIdx.y, gs = blockIdx.x;   // gs 0..15
    us* op = out + ((size_t)e * NB1 + nbx) * PANEL1_SH + (size_t)gs * 8 * 256 * 8;
    const float* w1e = w1 + (size_t)e * DIM * HID;
    const float* w2e = w2 + (size_t)e * DIM * HID;
    const int t = threadIdx.x;
#pragma unroll
    for (int it = 0; it < 8; it++) {
        int idx = it * 256 + t;          // 0..2047 = g(8) x row(256)
        int g = idx >> 8, row = idx & 255;
        int col = nbx * 128 + (row & 127);
        const float* src = (row < 128 ? w1e : w2e) + (size_t)((gs * 8 + g) * 8) * HID + col;
        short8 v;
#pragma unroll
        for (int s = 0; s < 8; s++) v[s] = (short)f2bf(src[(size_t)s * HID]);
        *(short8*)(op + (size_t)idx * 8) = v;
    }
}

// ---------------- w3 -> [e][nbx4][g256][row256][8] ----------------
__global__ __launch_bounds__(256) void wswz3_kernel(
    const float* __restrict__ w3, us* __restrict__ out)
{
    const int e = blockIdx.z, nbx = blockIdx.y, gs = blockIdx.x;   // gs 0..31
    us* op = out + ((size_t)e * NB2 + nbx) * PANEL3_SH + (size_t)gs * 8 * 256 * 8;
    const float* w3e = w3 + (size_t)e * HID * DIM;
    const int t = threadIdx.x;
#pragma unroll
    for (int it = 0; it < 8; it++) {
        int idx = it * 256 + t;
        int g = idx >> 8, row = idx & 255;
        int col = nbx * 256 + row;
        const float* src = w3e + (size_t)((gs * 8 + g) * 8) * DIM + col;
        short8 v;
#pragma unroll
        for (int s = 0; s < 8; s++) v[s] = (short)f2bf(src[(size_t)s * DIM]);
        *(short8*)(op + (size_t)idx * 8) = v;
    }
}

// ---------------- pass A: Xg @ [W1|W2] -> swiglu -> Hsw ----------------
__global__ __launch_bounds__(512, 2) void ffn1_mfma_kernel(
    const us* __restrict__ Xbf, const us* __restrict__ W12sw,
    const float* __restrict__ b1, const float* __restrict__ b2,
    const int* __restrict__ counts, const int* __restrict__ lists, const int* __restrict__ base,
    us* __restrict__ Hsw)
{
    const int e = blockIdx.z;
    const int cnt = counts[e];
    const int m0 = blockIdx.y * 256;
    if (m0 >= cnt) return;
    const int nbx = blockIdx.x;

    __shared__ __align__(16) unsigned char SM[133120];
    int* rowids = (int*)(SM + 132096);

    const int t = threadIdx.x;
    if (t < 256) {
        int idx = m0 + t;
        rowids[t] = (idx < cnt) ? lists[e * N_TOK + idx] : 0;   // clamp tail to a valid row
    }

    const int lane = t & 63, wv = t >> 6;
    const int wr = wv >> 2, wc = wv & 3;            // 2M x 4N
    const int Mw = wr * 128, Nw = wc * 64;
    const int fr = lane & 15, kc = lane >> 4;

    float bb[4];
    {
        const float* bsrc = (wc < 2) ? b1 : b2;
#pragma unroll
        for (int ni = 0; ni < 4; ni++)
            bb[ni] = bsrc[e * HID + nbx * 128 + (wc & 1) * 64 + ni * 16 + fr];
    }
    __syncthreads();   // rowids visible; vmcnt drained

    const int c0 = (wv)*128 + lane;
    const int c1 = c0 + 64;
    const int r0 = c0 & 255, r1 = c1 & 255;
    const us* ApA = Xbf + (size_t)(rowids[r0] >> 1) * DIM + (c0 >> 8) * 8;
    const us* ApB = Xbf + (size_t)(rowids[r1] >> 1) * DIM + (c1 >> 8) * 8;
    const us* Wp = W12sw + ((size_t)e * NB1 + nbx) * PANEL1_SH;
    const int dbase = (wv)*128 * 8;                 // wave-uniform LDS short base

    f32x4 acc[8][4];
    const f32x4 fz = {0.f, 0.f, 0.f, 0.f};
#pragma unroll
    for (int i = 0; i < 8; i++)
#pragma unroll
        for (int j = 0; j < 4; j++) acc[i][j] = fz;

    #define ABUF(b) ((us*)(SM + (b)*32768))
    #define BBUF(b) ((us*)(SM + 65536 + (b)*32768))

    #define STAGE_A(b, tile, h) do {                                         \
        gl_lds16(ApA + (tile)*64 + (h)*32, ABUF(b) + ((h)*1024)*8 + dbase);  \
        gl_lds16(ApB + (tile)*64 + (h)*32, ABUF(b) + ((h)*1024 + 64)*8 + dbase); \
    } while (0)
    #define STAGE_B(b, tile, h) do {                                         \
        const us* s_ = Wp + ((size_t)(tile)*2048 + (h)*1024) * 8;            \
        gl_lds16(s_ + (size_t)c0 * 8, BBUF(b) + ((h)*1024)*8 + dbase);       \
        gl_lds16(s_ + (size_t)c1 * 8, BBUF(b) + ((h)*1024 + 64)*8 + dbase);  \
    } while (0)

    #define AF_READ(b, h) do {                                               \
        _Pragma("unroll")                                                    \
        for (int mi = 0; mi < 8; mi++)                                       \
            af[mi] = *(const short8*)(ABUF(b) + ((h)*1024 + kc*256 + Mw + mi*16 + fr)*8); \
    } while (0)
    #define BF_READ(b, h, nh) do {                                           \
        bf[0] = *(const short8*)(BBUF(b) + ((h)*1024 + kc*256 + Nw + (nh)*32 + fr)*8); \
        bf[1] = *(const short8*)(BBUF(b) + ((h)*1024 + kc*256 + Nw + (nh)*32 + 16 + fr)*8); \
    } while (0)
    #define CLUST(nh) do {                                                   \
        PRIO1;                                                               \
        _Pragma("unroll")                                                    \
        for (int ni = 0; ni < 2; ni++) {                                     \
            _Pragma("unroll")                                                \
            for (int mi = 0; mi < 8; mi++)                                   \
                acc[mi][(nh)*2 + ni] = __builtin_amdgcn_mfma_f32_16x16x32_bf16( \
                    af[mi], bf[ni], acc[mi][(nh)*2 + ni], 0, 0, 0);          \
        }                                                                    \
        PRIO0;                                                               \
    } while (0)

    short8 af[8], bf[2];

    STAGE_A(0, 0, 0); STAGE_B(0, 0, 0); STAGE_A(0, 0, 1); STAGE_B(0, 0, 1);
    VMW4; BARM;

    for (int tl = 0; tl < NT1; ++tl) {
        const int b = tl & 1, nb = b ^ 1;
        const bool more = (tl + 1 < NT1);
        AF_READ(b, 0); BF_READ(b, 0, 0);
        if (more) STAGE_A(nb, tl + 1, 0);
        BARM; CLUST(0); BARM;
        BF_READ(b, 0, 1);
        if (more) { STAGE_B(nb, tl + 1, 0); VMW4; } else { VMW0; }
        BARM; CLUST(1); BARM;
        AF_READ(b, 1); BF_READ(b, 1, 0);
        if (more) STAGE_A(nb, tl + 1, 1);
        BARM; CLUST(0); BARM;
        BF_READ(b, 1, 1);
        if (more) { STAGE_B(nb, tl + 1, 1); VMW4; }
        BARM; CLUST(1); BARM;
    }

    // ---- SwiGLU epilogue via LDS gate exchange ----
    float* G = (float*)SM;                      // [256][129] f32 = 132096 B
    const int padcnt = (cnt + 127) & ~127;
    if (wc >= 2) {
        const int cp = wc - 2;
#pragma unroll
        for (int ni = 0; ni < 4; ni++) {
            int c2 = cp * 64 + ni * 16 + fr;
#pragma unroll
            for (int mi = 0; mi < 8; mi++) {
#pragma unroll
                for (int j = 0; j < 4; j++) {
                    int m = mi * 16 + kc * 4 + j;
                    float g = 1.f / (1.f + __expf(-(acc[mi][ni][j] + bb[ni])));
                    G[(wr * 128 + c2) * 129 + m] = g;
                }
            }
        }
    }
    __syncthreads();
    if (wc < 2) {
#pragma unroll
        for (int ni = 0; ni < 4; ni++) {
            int c2 = wc * 64 + ni * 16 + fr;
            int ch = nbx * 128 + c2;
            size_t cb = (size_t)(ch >> 3) * 128 * 8 + (ch & 7);
#pragma unroll
            for (int mi = 0; mi < 8; mi++) {
#pragma unroll
                for (int j = 0; j < 4; j++) {
                    int m = mi * 16 + kc * 4 + j;
                    int rl = wr * 128 + m;
                    if (m0 + rl >= padcnt) continue;
                    float h = (acc[mi][ni][j] + bb[ni]) * G[(wr * 128 + c2) * 129 + m];
                    int R = base[e] + m0 + rl;
                    Hsw[(size_t)(R >> 7) * HBLK_SH + cb + (size_t)(R & 127) * 8] = f2bf(h);
                }
            }
        }
    }
    #undef STAGE_A
    #undef STAGE_B
}

// ---------------- pass B: Hsw @ w3 -> f32 partials P (no atomics) ----------------
// 512-col pass (pan0 = 0 or 2): P[gpos][col - pan0*256..+512)
__global__ __launch_bounds__(512, 2) void ffn2_mfma_kernel(
    const us* __restrict__ Hsw, const us* __restrict__ W3sw, const float* __restrict__ b3,
    const int* __restrict__ counts, const int* __restrict__ lists, const float* __restrict__ wts,
    const int* __restrict__ base, const int* __restrict__ base_exact,
    float* __restrict__ P, int pan0)
{
    const int e = blockIdx.z;
    const int cnt = counts[e];
    const int m0 = blockIdx.y * 256;
    if (m0 >= cnt) return;
    const int nbx = pan0 + blockIdx.x;          // global 256-col panel idx

    __shared__ __align__(16) unsigned char SM[133120];
    int* rowids = (int*)(SM + 131072);
    float* rowwt = (float*)(SM + 132096);

    const int t = threadIdx.x;
    if (t < 256) {
        int idx = m0 + t;
        if (idx < cnt) { rowids[t] = lists[e * N_TOK + idx]; rowwt[t] = wts[e * N_TOK + idx]; }
        else           { rowids[t] = -1; rowwt[t] = 0.f; }
    }

    const int lane = t & 63, wv = t >> 6;
    const int wr = wv >> 2, wc = wv & 3;
    const int Mw = wr * 128, Nw = wc * 64;
    const int fr = lane & 15, kc = lane >> 4;

    float bb3[4];
#pragma unroll
    for (int ni = 0; ni < 4; ni++)
        bb3[ni] = b3[e * DIM + nbx * 256 + wc * 64 + ni * 16 + fr];
    __syncthreads();

    const int c0 = (wv)*128 + lane;
    const int c1 = c0 + 64;
    const int r0 = c0 & 255, r1 = c1 & 255;
    const int blk0 = (base[e] + m0) >> 7;
    const us* HpA = Hsw + (size_t)(blk0 + (r0 >> 7)) * HBLK_SH + ((c0 >> 8) * 128 + (r0 & 127)) * 8;
    const us* HpB = Hsw + (size_t)(blk0 + (r1 >> 7)) * HBLK_SH + ((c1 >> 8) * 128 + (r1 & 127)) * 8;
    const us* Wp = W3sw + ((size_t)e * NB2 + nbx) * PANEL3_SH;
    const int dbase = (wv)*128 * 8;

    f32x4 acc[8][4];
    const f32x4 fz = {0.f, 0.f, 0.f, 0.f};
#pragma unroll
    for (int i = 0; i < 8; i++)
#pragma unroll
        for (int j = 0; j < 4; j++) acc[i][j] = fz;

    #define STAGE_A2(b, tile, h) do {                                            \
        gl_lds16(HpA + ((size_t)(tile)*1024 + (h)*512) * 8, ABUF(b) + ((h)*1024)*8 + dbase); \
        gl_lds16(HpB + ((size_t)(tile)*1024 + (h)*512) * 8, ABUF(b) + ((h)*1024 + 64)*8 + dbase); \
    } while (0)
    #define STAGE_B2(b, tile, h) do {                                            \
        const us* s_ = Wp + ((size_t)(tile)*2048 + (h)*1024) * 8;                \
        gl_lds16(s_ + (size_t)c0 * 8, BBUF(b) + ((h)*1024)*8 + dbase);           \
        gl_lds16(s_ + (size_t)c1 * 8, BBUF(b) + ((h)*1024 + 64)*8 + dbase);      \
    } while (0)

    short8 af[8], bf[2];

    STAGE_A2(0, 0, 0); STAGE_B2(0, 0, 0); STAGE_A2(0, 0, 1); STAGE_B2(0, 0, 1);
    VMW4; BARM;

    for (int tl = 0; tl < NT2; ++tl) {
        const int b = tl & 1, nb = b ^ 1;
        const bool more = (tl + 1 < NT2);
        AF_READ(b, 0); BF_READ(b, 0, 0);
        if (more) STAGE_A2(nb, tl + 1, 0);
        BARM; CLUST(0); BARM;
        BF_READ(b, 0, 1);
        if (more) { STAGE_B2(nb, tl + 1, 0); VMW4; } else { VMW0; }
        BARM; CLUST(1); BARM;
        AF_READ(b, 1); BF_READ(b, 1, 0);
        if (more) STAGE_A2(nb, tl + 1, 1);
        BARM; CLUST(0); BARM;
        BF_READ(b, 1, 1);
        if (more) { STAGE_B2(nb, tl + 1, 1); VMW4; }
        BARM; CLUST(1); BARM;
    }

    // epilogue: f32 partials, conflict-free coalesced stores
#pragma unroll
    for (int ni = 0; ni < 4; ni++) {
        int cp = blockIdx.x * 256 + wc * 64 + ni * 16 + fr;   // col within 512-pass
#pragma unroll
        for (int mi = 0; mi < 8; mi++) {
#pragma unroll
            for (int j = 0; j < 4; j++) {
                int rl = wr * 128 + mi * 16 + kc * 4 + j;
                int rid = rowids[rl];
                if (rid < 0) continue;
                float v = (acc[mi][ni][j] + bb3[ni]) * rowwt[rl];
                P[(size_t)(base_exact[e] + m0 + rl) * 512 + cp] = v;
            }
        }
    }
    #undef STAGE_A2
    #undef STAGE_B2
}

// out[tok][colbase + c] = P[inv[2t]][c] + P[inv[2t+1]][c]
__global__ __launch_bounds__(256) void combine_kernel(
    const float* __restrict__ P, const int* __restrict__ inv,
    float* __restrict__ out, int colbase)
{
    int gid = blockIdx.x * 256 + threadIdx.x;
    int tok = gid >> 7;
    int c4 = (gid & 127) * 4;
    const float4 a = *(const float4*)(P + (size_t)inv[tok * 2] * 512 + c4);
    const float4 b = *(const float4*)(P + (size_t)inv[tok * 2 + 1] * 512 + c4);
    float4 r = make_float4(a.x + b.x, a.y + b.y, a.z + b.z, a.w + b.w);
    *(float4*)(out + (size_t)tok * DIM + colbase + c4) = r;
}

// ---------------- DIAGNOSTIC: ffn1 K-loop without staging/vmcnt (scratch output) ----------------
__global__ __launch_bounds__(512, 2) void ffn1_nostage_diag(
    const us* __restrict__ Xbf, const us* __restrict__ W12sw,
    const int* __restrict__ counts, const int* __restrict__ lists,
    float* __restrict__ scratch)
{
    const int e = blockIdx.z;
    const int cnt = counts[e];
    const int m0 = blockIdx.y * 256;
    if (m0 >= cnt) return;
    const int nbx = blockIdx.x;

    __shared__ __align__(16) unsigned char SM[133120];
    int* rowids = (int*)(SM + 132096);
    const int t = threadIdx.x;
    if (t < 256) {
        int idx = m0 + t;
        rowids[t] = (idx < cnt) ? lists[e * N_TOK + idx] : 0;
    }
    __syncthreads();

    const int lane = t & 63, wv = t >> 6;
    const int wr = wv >> 2, wc = wv & 3;
    const int Mw = wr * 128, Nw = wc * 64;
    const int fr = lane & 15, kc = lane >> 4;
    const int c0 = wv * 128 + lane, c1 = c0 + 64;
    const int r0 = c0 & 255, r1 = c1 & 255;
    const us* ApA = Xbf + (size_t)(rowids[r0] >> 1) * DIM + (c0 >> 8) * 8;
    const us* ApB = Xbf + (size_t)(rowids[r1] >> 1) * DIM + (c1 >> 8) * 8;
    const us* Wp = W12sw + ((size_t)e * NB1 + nbx) * PANEL1_SH;
    const int dbase = wv * 128 * 8;

    f32x4 acc[8][4];
    const f32x4 fz = {0.f, 0.f, 0.f, 0.f};
#pragma unroll
    for (int i = 0; i < 8; i++)
#pragma unroll
        for (int j = 0; j < 4; j++) acc[i][j] = fz;

    // stage tile 0 only
    gl_lds16(ApA, ABUF(0) + dbase);
    gl_lds16(ApB, ABUF(0) + 64 * 8 + dbase);
    gl_lds16(ApA + 32, ABUF(0) + 1024 * 8 + dbase);
    gl_lds16(ApB + 32, ABUF(0) + (1024 + 64) * 8 + dbase);
    gl_lds16(Wp + (size_t)c0 * 8, BBUF(0) + dbase);
    gl_lds16(Wp + (size_t)c1 * 8, BBUF(0) + 64 * 8 + dbase);
    gl_lds16(Wp + (size_t)(1024 + c0) * 8, BBUF(0) + 1024 * 8 + dbase);
    gl_lds16(Wp + (size_t)(1024 + c1) * 8, BBUF(0) + (1024 + 64) * 8 + dbase);
    VMW0; BARM;

    short8 af[8], bf[2];
    for (int tl = 0; tl < NT1; ++tl) {
        const int b = tl & 1;
        AF_READ(b, 0); BF_READ(b, 0, 0);
        BARM; CLUST(0); BARM;
        BF_READ(b, 0, 1);
        BARM; CLUST(1); BARM;
        AF_READ(b, 1); BF_READ(b, 1, 0);
        BARM; CLUST(0); BARM;
        BF_READ(b, 1, 1);
        BARM; CLUST(1); BARM;
    }

    f32x4 s = fz;
#pragma unroll
    for (int i = 0; i < 8; i++)
#pragma unroll
        for (int j = 0; j < 4; j++) {
            s[0] += acc[i][j][0]; s[1] += acc[i][j][1];
            s[2] += acc[i][j][2]; s[3] += acc[i][j][3];
        }
    int lin = ((int)blockIdx.z * 64 + (int)blockIdx.y) * 16 + nbx;
    *(f32x4*)(scratch + ((size_t)lin * 512 + t) * 4) = s;
}

extern "C" void kernel_launch(void* const* d_in, const int* in_sizes, int n_in,
                              void* d_out, int out_size, void* d_ws, size_t ws_size,
                              hipStream_t stream) {
    (void)in_sizes; (void)n_in; (void)out_size; (void)ws_size;
    const float* x      = (const float*)d_in[0];
    const float* gate_w = (const float*)d_in[1];
    const float* gate_b = (const float*)d_in[2];
    const float* w1     = (const float*)d_in[3];
    const float* b1     = (const float*)d_in[4];
    const float* w2     = (const float*)d_in[5];
    const float* b2     = (const float*)d_in[6];
    const float* w3     = (const float*)d_in[7];
    const float* b3     = (const float*)d_in[8];
    float* out = (float*)d_out;

    char* ws = (char*)d_ws;
    float* usage      = (float*)ws;                               // @0, 32 B
    int*   counts     = (int*)(ws + 32);                          // @32, 32 B
    int*   base       = (int*)(ws + 64);                          // @64, 32 B
    int*   base_exact = (int*)(ws + 96);                          // @96, 32 B
    int*   lists      = (int*)(ws + 128);                         // 256 KB
    float* wts        = (float*)(ws + 128 + (size_t)NE * N_TOK * 4);   // 256 KB
    int*   inv        = (int*)(ws + 128 + (size_t)2 * NE * N_TOK * 4); // 64 KB
    us* Hsw   = (us*)(ws + (1ull  << 20));                        // @1 MiB, <=68 MiB
    us* W12sw = (us*)(ws + (69ull << 20));                        // @69 MiB, 64 MiB (ffn1 phase)
    us* W3sw  = W12sw;                                            // @69 MiB, 32 MiB (ffn2 phase)
    float* P  = (float*)(ws + (101ull << 20));                    // @101 MiB, 32 MiB (ffn2 phase)
    us* Xbf   = (us*)d_out;                                       // 16 MiB, pre-combine

    hipMemsetAsync(ws, 0, 128, stream);

    gate_kernel<<<N_TOK / 4, 256, 0, stream>>>(x, gate_w, gate_b, usage, counts, lists, wts, Xbf);
    prefix_kernel<<<1, 64, 0, stream>>>(counts, base, base_exact);
    {
        dim3 gI(N_TOK / 256, NE);
        inv_kernel<<<gI, 256, 0, stream>>>(counts, lists, base_exact, inv);
    }

    dim3 gW12(16, NB1, NE);
    wswz12_kernel<<<gW12, 256, 0, stream>>>(w1, w2, W12sw);

    dim3 gA(NB1, 64, NE);
    ffn1_mfma_kernel<<<gA, 512, 0, stream>>>(Xbf, W12sw, b1, b2, counts, lists, base, Hsw);

    loss_kernel<<<1, 64, 0, stream>>>(usage, out + (size_t)N_TOK * DIM);

    dim3 gW3(32, NB2, NE);
    wswz3_kernel<<<gW3, 256, 0, stream>>>(w3, W3sw);

    dim3 gB(2, 64, NE);
    ffn2_mfma_kernel<<<gB, 512, 0, stream>>>(Hsw, W3sw, b3, counts, lists, wts,
                                             base, base_exact, P, 0);
    combine_kernel<<<N_TOK * 128 / 256, 256, 0, stream>>>(P, inv, out, 0);
    ffn2_mfma_kernel<<<gB, 512, 0, stream>>>(Hsw, W3sw, b3, counts, lists, wts,
                                             base, base_exact, P, 2);
    combine_kernel<<<N_TOK * 128 / 256, 256, 0, stream>>>(P, inv, out, 512);

    // diagnostic (scratch = P region, free after combines); experts 0-1 only (~1 generation)
    dim3 gD(NB1, 64, 2);
    ffn1_nostage_diag<<<gD, 512, 0, stream>>>(Xbf, W12sw, counts, lists, P);
}

// Round 12
// 680.059 us; speedup vs baseline: 1.0546x; 1.0327x over previous
//
#include <hip/hip_runtime.h>
#include <hip/hip_bf16.h>
#include <math.h>

#define N_TOK 8192
#define DIM   1024
#define HID   2048
#define NE    8
#define NT1   16     // DIM/64 K-tiles (ffn1)
#define NT2   32     // HID/64 K-tiles (ffn2)
#define NB1   16     // HID/128 panels (ffn1)
#define NB2   4      // DIM/256 panels (ffn2)
#define MAXT  72     // max (e,m0) tiles: 16384/256 + 8
#define PANEL1_SH ((size_t)(128 * 256 * 8))   // shorts per ffn1 [W1|W2] panel (512KB)
#define PANEL3_SH ((size_t)(256 * 256 * 8))   // shorts per w3 256-col panel (1MB)
#define XBLK_SH   ((size_t)(128 * 128 * 8))   // shorts per 128-row Xg block (256KB)
#define HBLK_SH   ((size_t)(256 * 128 * 8))   // shorts per 128-row Hsw block (512KB)

typedef __attribute__((ext_vector_type(8))) short short8;
typedef __attribute__((ext_vector_type(4))) float f32x4;
typedef unsigned short us;

__device__ __forceinline__ us f2bf(float f) {
    unsigned int u = __builtin_bit_cast(unsigned int, f);
    unsigned int r = (u + 0x7fffu + ((u >> 16) & 1u)) >> 16;   // RNE
    return (us)r;
}

__device__ __forceinline__ void gl_lds16(const us* g, us* l) {
    __builtin_amdgcn_global_load_lds(
        (const __attribute__((address_space(1))) void*)g,
        (__attribute__((address_space(3))) void*)l, 16, 0, 0);
}

#define VMW4 asm volatile("s_waitcnt vmcnt(4)" ::: "memory")
#define VMW0 asm volatile("s_waitcnt vmcnt(0)" ::: "memory")
#define BARM asm volatile("s_barrier" ::: "memory")
#define PRIO1 __builtin_amdgcn_s_setprio(1)
#define PRIO0 __builtin_amdgcn_s_setprio(0)

// ---------------- gating ----------------
__global__ __launch_bounds__(256) void gate_kernel(
    const float* __restrict__ x, const float* __restrict__ gw, const float* __restrict__ gb,
    float* __restrict__ usage, int* __restrict__ counts,
    int* __restrict__ lists, float* __restrict__ wts)
{
    const int lane = threadIdx.x & 63;
    const int tok = blockIdx.x * 4 + (threadIdx.x >> 6);

    __shared__ float su[NE];
    if (threadIdx.x < NE) su[threadIdx.x] = 0.f;
    __syncthreads();

    float acc[NE];
#pragma unroll
    for (int e = 0; e < NE; e++) acc[e] = 0.f;

    const float* xr = x + (size_t)tok * DIM;
    for (int d = lane; d < DIM; d += 64) {
        float xv = xr[d];
        const float4* g4 = (const float4*)(gw + (size_t)d * NE);
        float4 ga = g4[0], gc = g4[1];
        acc[0] = fmaf(xv, ga.x, acc[0]);
        acc[1] = fmaf(xv, ga.y, acc[1]);
        acc[2] = fmaf(xv, ga.z, acc[2]);
        acc[3] = fmaf(xv, ga.w, acc[3]);
        acc[4] = fmaf(xv, gc.x, acc[4]);
        acc[5] = fmaf(xv, gc.y, acc[5]);
        acc[6] = fmaf(xv, gc.z, acc[6]);
        acc[7] = fmaf(xv, gc.w, acc[7]);
    }
#pragma unroll
    for (int e = 0; e < NE; e++) {
#pragma unroll
        for (int off = 32; off > 0; off >>= 1)
            acc[e] += __shfl_xor(acc[e], off);
    }

    if (lane == 0) {
        float lg[NE], p[NE];
        float mx = -1e30f;
#pragma unroll
        for (int e = 0; e < NE; e++) { lg[e] = acc[e] + gb[e]; mx = fmaxf(mx, lg[e]); }
        float s = 0.f;
#pragma unroll
        for (int e = 0; e < NE; e++) { p[e] = __expf(lg[e] - mx); s += p[e]; }
        float inv = 1.f / s;
#pragma unroll
        for (int e = 0; e < NE; e++) p[e] *= inv;
#pragma unroll
        for (int e = 0; e < NE; e++) atomicAdd(&su[e], p[e]);

        int e1 = 0; float v1 = p[0];
#pragma unroll
        for (int e = 1; e < NE; e++) if (p[e] > v1) { v1 = p[e]; e1 = e; }
        int e2 = -1; float v2 = -1e30f;
#pragma unroll
        for (int e = 0; e < NE; e++) if (e != e1 && p[e] > v2) { v2 = p[e]; e2 = e; }

        int pos1 = atomicAdd(&counts[e1], 1);
        lists[e1 * N_TOK + pos1] = tok * 2 + 0;
        wts[e1 * N_TOK + pos1] = v1;
        int pos2 = atomicAdd(&counts[e2], 1);
        lists[e2 * N_TOK + pos2] = tok * 2 + 1;
        wts[e2 * N_TOK + pos2] = v2;
    }
    __syncthreads();
    if (threadIdx.x < NE) atomicAdd(&usage[threadIdx.x], su[threadIdx.x]);
}

__global__ void loss_kernel(const float* __restrict__ usage, float* __restrict__ out_loss)
{
    if (threadIdx.x == 0) {
        float l = 0.f;
        for (int e = 0; e < NE; e++) {
            float u = usage[e] / (float)N_TOK;
            l += u * logf(u + 1e-9f);
        }
        *out_loss = l;
    }
}

// exact prefix + dense (e, m0) tile worklist
__global__ void prefix_kernel(const int* __restrict__ counts,
                              int* __restrict__ base_exact, int* __restrict__ ntiles,
                              int* __restrict__ tmap_e, int* __restrict__ tmap_m0)
{
    if (threadIdx.x == 0) {
        int bx = 0, nt = 0;
        for (int e = 0; e < NE; e++) {
            base_exact[e] = bx;
            for (int m0 = 0; m0 < counts[e]; m0 += 256) {
                tmap_e[nt] = e; tmap_m0[nt] = m0; nt++;
            }
            bx += counts[e];
        }
        ntiles[0] = nt;
    }
}

// inv[rid] = global list position of routing entry rid
__global__ __launch_bounds__(256) void inv_kernel(
    const int* __restrict__ counts, const int* __restrict__ lists,
    const int* __restrict__ base_exact, int* __restrict__ inv)
{
    const int e = blockIdx.y;
    const int idx = blockIdx.x * 256 + threadIdx.x;
    if (idx < counts[e]) inv[lists[e * N_TOK + idx]] = base_exact[e] + idx;
}

// ---------------- X pre-gather: x (f32, token order) -> Xg (bf16, routing order, chunk-tiled) ----------------
// Xg layout: [gpos>>7][chunk 0..127][gpos&127][8]
__global__ __launch_bounds__(256) void xgather_kernel(
    const float* __restrict__ x,
    const int* __restrict__ counts, const int* __restrict__ lists,
    const int* __restrict__ base_exact,
    us* __restrict__ Xg)
{
    __shared__ int toks[128];
    __shared__ int bexs[NE], cnts[NE];
    const int t = threadIdx.x;
    if (t < NE) { bexs[t] = base_exact[t]; cnts[t] = counts[t]; }
    __syncthreads();
    if (t < 128) {
        int gpos = blockIdx.x * 128 + t;
        int e = 0;
#pragma unroll
        for (int k = 1; k < NE; k++) if (gpos >= bexs[k]) e = k;
        int idx = gpos - bexs[e];
        int tok = (idx < cnts[e]) ? (lists[e * N_TOK + idx] >> 1) : 0;
        toks[t] = tok;
    }
    __syncthreads();

    us* op = Xg + (size_t)blockIdx.x * XBLK_SH;
    const int rr = t & 127;
    const int ch = t >> 7;                 // 0/1
    const int tok = toks[rr];
#pragma unroll
    for (int it = 0; it < 64; it++) {
        int c = it * 2 + ch;               // chunk 0..127
        const float4* src = (const float4*)(x + (size_t)tok * DIM + c * 8);
        float4 a = src[0], b = src[1];
        short8 v;
        v[0] = (short)f2bf(a.x); v[1] = (short)f2bf(a.y);
        v[2] = (short)f2bf(a.z); v[3] = (short)f2bf(a.w);
        v[4] = (short)f2bf(b.x); v[5] = (short)f2bf(b.y);
        v[6] = (short)f2bf(b.z); v[7] = (short)f2bf(b.w);
        *(short8*)(op + (size_t)(c * 128 + rr) * 8) = v;
    }
}

// ---------------- w1,w2 -> [e][nbx16][g128][row256][8], rows = [W1 128 | W2 128] ----------------
__global__ __launch_bounds__(256) void wswz12_kernel(
    const float* __restrict__ w1, const float* __restrict__ w2, us* __restrict__ out)
{
    const int e = blockIdx.z, nbx = blockIdx.y, gs = blockIdx.x;   // gs 0..15
    us* op = out + ((size_t)e * NB1 + nbx) * PANEL1_SH + (size_t)gs * 8 * 256 * 8;
    const float* w1e = w1 + (size_t)e * DIM * HID;
    const float* w2e = w2 + (size_t)e * DIM * HID;
    const int t = threadIdx.x;
#pragma unroll
    for (int it = 0; it < 8; it++) {
        int idx = it * 256 + t;
        int g = idx >> 8, row = idx & 255;
        int col = nbx * 128 + (row & 127);
        const float* src = (row < 128 ? w1e : w2e) + (size_t)((gs * 8 + g) * 8) * HID + col;
        short8 v;
#pragma unroll
        for (int s = 0; s < 8; s++) v[s] = (short)f2bf(src[(size_t)s * HID]);
        *(short8*)(op + (size_t)idx * 8) = v;
    }
}

// ---------------- w3 -> [e][nbx4][g256][row256][8] ----------------
__global__ __launch_bounds__(256) void wswz3_kernel(
    const float* __restrict__ w3, us* __restrict__ out)
{
    const int e = blockIdx.z, nbx = blockIdx.y, gs = blockIdx.x;   // gs 0..31
    us* op = out + ((size_t)e * NB2 + nbx) * PANEL3_SH + (size_t)gs * 8 * 256 * 8;
    const float* w3e = w3 + (size_t)e * HID * DIM;
    const int t = threadIdx.x;
#pragma unroll
    for (int it = 0; it < 8; it++) {
        int idx = it * 256 + t;
        int g = idx >> 8, row = idx & 255;
        int col = nbx * 256 + row;
        const float* src = w3e + (size_t)((gs * 8 + g) * 8) * DIM + col;
        short8 v;
#pragma unroll
        for (int s = 0; s < 8; s++) v[s] = (short)f2bf(src[(size_t)s * DIM]);
        *(short8*)(op + (size_t)idx * 8) = v;
    }
}

#define ABUF(b) ((us*)(SM + (b)*32768))
#define BBUF(b) ((us*)(SM + 65536 + (b)*32768))

#define AF_READ(b, h) do {                                               \
    _Pragma("unroll")                                                    \
    for (int mi = 0; mi < 8; mi++)                                       \
        af[mi] = *(const short8*)(ABUF(b) + ((h)*1024 + kc*256 + Mw + mi*16 + fr)*8); \
} while (0)
#define BF_READ(b, h, nh) do {                                           \
    bf[0] = *(const short8*)(BBUF(b) + ((h)*1024 + kc*256 + Nw + (nh)*32 + fr)*8); \
    bf[1] = *(const short8*)(BBUF(b) + ((h)*1024 + kc*256 + Nw + (nh)*32 + 16 + fr)*8); \
} while (0)
#define CLUST(nh) do {                                                   \
    PRIO1;                                                               \
    _Pragma("unroll")                                                    \
    for (int ni = 0; ni < 2; ni++) {                                     \
        _Pragma("unroll")                                                \
        for (int mi = 0; mi < 8; mi++)                                   \
            acc[mi][(nh)*2 + ni] = __builtin_amdgcn_mfma_f32_16x16x32_bf16( \
                af[mi], bf[ni], acc[mi][(nh)*2 + ni], 0, 0, 0);          \
    }                                                                    \
    PRIO0;                                                               \
} while (0)

// ---------------- pass A: Xg @ [W1|W2] -> swiglu -> Hsw (exact order) ----------------
__global__ __launch_bounds__(512, 2) void ffn1_mfma_kernel(
    const us* __restrict__ Xg, const us* __restrict__ W12sw,
    const float* __restrict__ b1, const float* __restrict__ b2,
    const int* __restrict__ counts, const int* __restrict__ base_exact,
    const int* __restrict__ ntiles, const int* __restrict__ tmap_e, const int* __restrict__ tmap_m0,
    us* __restrict__ Hsw)
{
    const int by = blockIdx.y;
    if (by >= ntiles[0]) return;
    const int e  = tmap_e[by];
    const int m0 = tmap_m0[by];
    const int cnt = counts[e];
    const int bex = base_exact[e];
    const int nbx = blockIdx.x;

    __shared__ __align__(16) unsigned char SM[132096];   // G exchange: 256x129 f32

    const int t = threadIdx.x;
    const int lane = t & 63, wv = t >> 6;
    const int wr = wv >> 2, wc = wv & 3;            // 2M x 4N
    const int Mw = wr * 128, Nw = wc * 64;
    const int fr = lane & 15, kc = lane >> 4;

    float bb[4];
    {
        const float* bsrc = (wc < 2) ? b1 : b2;
#pragma unroll
        for (int ni = 0; ni < 4; ni++)
            bb[ni] = bsrc[e * HID + nbx * 128 + (wc & 1) * 64 + ni * 16 + fr];
    }
    __syncthreads();   // drain bias loads (vmcnt=0 before pipeline)

    // linear A addressing over exact routing-order Xg
    const int c0 = wv * 128 + lane;
    const int c1 = c0 + 64;
    const int RA0 = min(bex + m0 + (c0 & 255), N_TOK * 2 - 1);
    const int RA1 = min(bex + m0 + (c1 & 255), N_TOK * 2 - 1);
    const us* ApA = Xg + (size_t)(RA0 >> 7) * XBLK_SH + (size_t)(c0 >> 8) * 1024 + (RA0 & 127) * 8;
    const us* ApB = Xg + (size_t)(RA1 >> 7) * XBLK_SH + (size_t)(c1 >> 8) * 1024 + (RA1 & 127) * 8;
    const us* Wp = W12sw + ((size_t)e * NB1 + nbx) * PANEL1_SH;
    const int dbase = wv * 128 * 8;

    f32x4 acc[8][4];
    const f32x4 fz = {0.f, 0.f, 0.f, 0.f};
#pragma unroll
    for (int i = 0; i < 8; i++)
#pragma unroll
        for (int j = 0; j < 4; j++) acc[i][j] = fz;

    #define STAGE_A(b, tile, h) do {                                             \
        gl_lds16(ApA + (size_t)((tile)*8 + (h)*4) * 1024, ABUF(b) + ((h)*1024)*8 + dbase); \
        gl_lds16(ApB + (size_t)((tile)*8 + (h)*4) * 1024, ABUF(b) + ((h)*1024 + 64)*8 + dbase); \
    } while (0)
    #define STAGE_B(b, tile, h) do {                                             \
        const us* s_ = Wp + ((size_t)(tile)*2048 + (h)*1024) * 8;                \
        gl_lds16(s_ + (size_t)c0 * 8, BBUF(b) + ((h)*1024)*8 + dbase);           \
        gl_lds16(s_ + (size_t)c1 * 8, BBUF(b) + ((h)*1024 + 64)*8 + dbase);      \
    } while (0)

    short8 af[8], bf[2];

    STAGE_A(0, 0, 0); STAGE_B(0, 0, 0); STAGE_A(0, 0, 1); STAGE_B(0, 0, 1);
    VMW4; BARM;

    for (int tl = 0; tl < NT1; ++tl) {
        const int b = tl & 1, nb = b ^ 1;
        const bool more = (tl + 1 < NT1);
        AF_READ(b, 0); BF_READ(b, 0, 0);
        if (more) STAGE_A(nb, tl + 1, 0);
        BARM; CLUST(0); BARM;
        BF_READ(b, 0, 1);
        if (more) { STAGE_B(nb, tl + 1, 0); VMW4; } else { VMW0; }
        BARM; CLUST(1); BARM;
        AF_READ(b, 1); BF_READ(b, 1, 0);
        if (more) STAGE_A(nb, tl + 1, 1);
        BARM; CLUST(0); BARM;
        BF_READ(b, 1, 1);
        if (more) { STAGE_B(nb, tl + 1, 1); VMW4; }
        BARM; CLUST(1); BARM;
    }
    #undef STAGE_A
    #undef STAGE_B

    // ---- SwiGLU epilogue via LDS gate exchange ----
    float* G = (float*)SM;                      // [256][129] f32
    if (wc >= 2) {
        const int cp = wc - 2;
#pragma unroll
        for (int ni = 0; ni < 4; ni++) {
            int c2 = cp * 64 + ni * 16 + fr;
#pragma unroll
            for (int mi = 0; mi < 8; mi++) {
#pragma unroll
                for (int j = 0; j < 4; j++) {
                    int m = mi * 16 + kc * 4 + j;
                    float g = 1.f / (1.f + __expf(-(acc[mi][ni][j] + bb[ni])));
                    G[(wr * 128 + c2) * 129 + m] = g;
                }
            }
        }
    }
    __syncthreads();
    if (wc < 2) {
#pragma unroll
        for (int ni = 0; ni < 4; ni++) {
            int c2 = wc * 64 + ni * 16 + fr;
            int ch = nbx * 128 + c2;
            size_t cb = (size_t)(ch >> 3) * 128 * 8 + (ch & 7);
#pragma unroll
            for (int mi = 0; mi < 8; mi++) {
#pragma unroll
                for (int j = 0; j < 4; j++) {
                    int m = mi * 16 + kc * 4 + j;
                    int rl = wr * 128 + m;
                    if (m0 + rl >= cnt) continue;
                    float h = (acc[mi][ni][j] + bb[ni]) * G[(wr * 128 + c2) * 129 + m];
                    int R = bex + m0 + rl;
                    Hsw[(size_t)(R >> 7) * HBLK_SH + cb + (size_t)(R & 127) * 8] = f2bf(h);
                }
            }
        }
    }
}

// ---------------- pass B: Hsw @ w3 -> f32 partials P ----------------
__global__ __launch_bounds__(512, 2) void ffn2_mfma_kernel(
    const us* __restrict__ Hsw, const us* __restrict__ W3sw, const float* __restrict__ b3,
    const int* __restrict__ counts, const int* __restrict__ base_exact,
    const int* __restrict__ ntiles, const int* __restrict__ tmap_e, const int* __restrict__ tmap_m0,
    const float* __restrict__ wts, const int* __restrict__ lists,
    float* __restrict__ P, int pan0)
{
    const int by = blockIdx.y;
    if (by >= ntiles[0]) return;
    const int e  = tmap_e[by];
    const int m0 = tmap_m0[by];
    const int cnt = counts[e];
    const int bex = base_exact[e];
    const int nbx = pan0 + blockIdx.x;

    __shared__ __align__(16) unsigned char SM[132096];
    float* rowwt = (float*)(SM + 131072);   // 256 f32

    const int t = threadIdx.x;
    if (t < 256) {
        int idx = m0 + t;
        rowwt[t] = (idx < cnt) ? wts[e * N_TOK + idx] : 0.f;
    }

    const int lane = t & 63, wv = t >> 6;
    const int wr = wv >> 2, wc = wv & 3;
    const int Mw = wr * 128, Nw = wc * 64;
    const int fr = lane & 15, kc = lane >> 4;

    float bb3[4];
#pragma unroll
    for (int ni = 0; ni < 4; ni++)
        bb3[ni] = b3[e * DIM + nbx * 256 + wc * 64 + ni * 16 + fr];
    __syncthreads();

    const int c0 = wv * 128 + lane;
    const int c1 = c0 + 64;
    const int RA0 = min(bex + m0 + (c0 & 255), N_TOK * 2 - 1);
    const int RA1 = min(bex + m0 + (c1 & 255), N_TOK * 2 - 1);
    const us* HpA = Hsw + (size_t)(RA0 >> 7) * HBLK_SH + (size_t)(c0 >> 8) * 1024 + (RA0 & 127) * 8;
    const us* HpB = Hsw + (size_t)(RA1 >> 7) * HBLK_SH + (size_t)(c1 >> 8) * 1024 + (RA1 & 127) * 8;
    const us* Wp = W3sw + ((size_t)e * NB2 + nbx) * PANEL3_SH;
    const int dbase = wv * 128 * 8;

    f32x4 acc[8][4];
    const f32x4 fz = {0.f, 0.f, 0.f, 0.f};
#pragma unroll
    for (int i = 0; i < 8; i++)
#pragma unroll
        for (int j = 0; j < 4; j++) acc[i][j] = fz;

    #define STAGE_A2(b, tile, h) do {                                            \
        gl_lds16(HpA + (size_t)((tile)*8 + (h)*4) * 1024, ABUF(b) + ((h)*1024)*8 + dbase); \
        gl_lds16(HpB + (size_t)((tile)*8 + (h)*4) * 1024, ABUF(b) + ((h)*1024 + 64)*8 + dbase); \
    } while (0)
    #define STAGE_B2(b, tile, h) do {                                            \
        const us* s_ = Wp + ((size_t)(tile)*2048 + (h)*1024) * 8;                \
        gl_lds16(s_ + (size_t)c0 * 8, BBUF(b) + ((h)*1024)*8 + dbase);           \
        gl_lds16(s_ + (size_t)c1 * 8, BBUF(b) + ((h)*1024 + 64)*8 + dbase);      \
    } while (0)

    short8 af[8], bf[2];

    STAGE_A2(0, 0, 0); STAGE_B2(0, 0, 0); STAGE_A2(0, 0, 1); STAGE_B2(0, 0, 1);
    VMW4; BARM;

    for (int tl = 0; tl < NT2; ++tl) {
        const int b = tl & 1, nb = b ^ 1;
        const bool more = (tl + 1 < NT2);
        AF_READ(b, 0); BF_READ(b, 0, 0);
        if (more) STAGE_A2(nb, tl + 1, 0);
        BARM; CLUST(0); BARM;
        BF_READ(b, 0, 1);
        if (more) { STAGE_B2(nb, tl + 1, 0); VMW4; } else { VMW0; }
        BARM; CLUST(1); BARM;
        AF_READ(b, 1); BF_READ(b, 1, 0);
        if (more) STAGE_A2(nb, tl + 1, 1);
        BARM; CLUST(0); BARM;
        BF_READ(b, 1, 1);
        if (more) { STAGE_B2(nb, tl + 1, 1); VMW4; }
        BARM; CLUST(1); BARM;
    }
    #undef STAGE_A2
    #undef STAGE_B2

#pragma unroll
    for (int ni = 0; ni < 4; ni++) {
        int cp = blockIdx.x * 256 + wc * 64 + ni * 16 + fr;   // col within 512-pass
#pragma unroll
        for (int mi = 0; mi < 8; mi++) {
#pragma unroll
            for (int j = 0; j < 4; j++) {
                int rl = wr * 128 + mi * 16 + kc * 4 + j;
                if (m0 + rl >= cnt) continue;
                float v = (acc[mi][ni][j] + bb3[ni]) * rowwt[rl];
                P[(size_t)(bex + m0 + rl) * 512 + cp] = v;
            }
        }
    }
}

// out[tok][colbase + c] = P[inv[2t]][c] + P[inv[2t+1]][c]
__global__ __launch_bounds__(256) void combine_kernel(
    const float* __restrict__ P, const int* __restrict__ inv,
    float* __restrict__ out, int colbase)
{
    int gid = blockIdx.x * 256 + threadIdx.x;
    int tok = gid >> 7;
    int c4 = (gid & 127) * 4;
    const float4 a = *(const float4*)(P + (size_t)inv[tok * 2] * 512 + c4);
    const float4 b = *(const float4*)(P + (size_t)inv[tok * 2 + 1] * 512 + c4);
    float4 r = make_float4(a.x + b.x, a.y + b.y, a.z + b.z, a.w + b.w);
    *(float4*)(out + (size_t)tok * DIM + colbase + c4) = r;
}

extern "C" void kernel_launch(void* const* d_in, const int* in_sizes, int n_in,
                              void* d_out, int out_size, void* d_ws, size_t ws_size,
                              hipStream_t stream) {
    (void)in_sizes; (void)n_in; (void)out_size; (void)ws_size;
    const float* x      = (const float*)d_in[0];
    const float* gate_w = (const float*)d_in[1];
    const float* gate_b = (const float*)d_in[2];
    const float* w1     = (const float*)d_in[3];
    const float* b1     = (const float*)d_in[4];
    const float* w2     = (const float*)d_in[5];
    const float* b2     = (const float*)d_in[6];
    const float* w3     = (const float*)d_in[7];
    const float* b3     = (const float*)d_in[8];
    float* out = (float*)d_out;

    char* ws = (char*)d_ws;
    float* usage      = (float*)ws;                               // @0, 32 B
    int*   counts     = (int*)(ws + 32);                          // @32, 32 B
    int*   base_exact = (int*)(ws + 64);                          // @64, 32 B
    int*   ntiles     = (int*)(ws + 96);                          // @96, 16 B
    int*   tmap_e     = (int*)(ws + 128);                         // 72*4 -> 512 B slot
    int*   tmap_m0    = (int*)(ws + 640);                         // 512 B
    int*   lists      = (int*)(ws + 4096);                        // 256 KB
    float* wts        = (float*)(ws + 4096 + (size_t)NE * N_TOK * 4);   // 256 KB
    int*   inv        = (int*)(ws + 4096 + (size_t)2 * NE * N_TOK * 4); // 64 KB
    us* Hsw   = (us*)(ws + (1ull  << 20));                        // @1 MiB, 64 MiB (exact)
    us* W12sw = (us*)(ws + (65ull << 20));                        // @65 MiB, 64 MiB (ffn1 phase)
    us* W3sw  = W12sw;                                            // @65 MiB, 32 MiB (ffn2 phase)
    float* P  = (float*)(ws + (97ull << 20));                     // @97 MiB, 32 MiB (ffn2 phase)
    us* Xg    = (us*)d_out;                                       // 32 MiB, routing-order X

    hipMemsetAsync(ws, 0, 128, stream);

    gate_kernel<<<N_TOK / 4, 256, 0, stream>>>(x, gate_w, gate_b, usage, counts, lists, wts);
    prefix_kernel<<<1, 64, 0, stream>>>(counts, base_exact, ntiles, tmap_e, tmap_m0);
    {
        dim3 gI(N_TOK / 256, NE);
        inv_kernel<<<gI, 256, 0, stream>>>(counts, lists, base_exact, inv);
    }
    xgather_kernel<<<N_TOK * 2 / 128, 256, 0, stream>>>(x, counts, lists, base_exact, Xg);

    dim3 gW12(16, NB1, NE);
    wswz12_kernel<<<gW12, 256, 0, stream>>>(w1, w2, W12sw);

    dim3 gA(NB1, MAXT, 1);
    ffn1_mfma_kernel<<<gA, 512, 0, stream>>>(Xg, W12sw, b1, b2, counts, base_exact,
                                             ntiles, tmap_e, tmap_m0, Hsw);

    loss_kernel<<<1, 64, 0, stream>>>(usage, out + (size_t)N_TOK * DIM);

    dim3 gW3(32, NB2, NE);
    wswz3_kernel<<<gW3, 256, 0, stream>>>(w3, W3sw);

    dim3 gB(2, MAXT, 1);
    ffn2_mfma_kernel<<<gB, 512, 0, stream>>>(Hsw, W3sw, b3, counts, base_exact,
                                             ntiles, tmap_e, tmap_m0, wts, lists, P, 0);
    combine_kernel<<<N_TOK * 128 / 256, 256, 0, stream>>>(P, inv, out, 0);
    ffn2_mfma_kernel<<<gB, 512, 0, stream>>>(Hsw, W3sw, b3, counts, base_exact,
                                             ntiles, tmap_e, tmap_m0, wts, lists, P, 2);
    combine_kernel<<<N_TOK * 128 / 256, 256, 0, stream>>>(P, inv, out, 512);
}

// Round 13
// 501.730 us; speedup vs baseline: 1.4295x; 1.3554x over previous
//
#include <hip/hip_runtime.h>
#include <hip/hip_bf16.h>
#include <math.h>

#define N_TOK 8192
#define DIM   1024
#define HID   2048
#define NE    8
#define NT1   16     // DIM/64 K-tiles (ffn1)
#define NT2   32     // HID/64 K-tiles (ffn2)
#define NB1   16     // HID/128 panels (ffn1)
#define NB2   4      // DIM/256 panels (ffn2)
#define MAXT  72     // max (e,m0) tiles
#define PANEL1_SH ((size_t)(128 * 256 * 8))   // shorts per ffn1 [W1|W2] panel (512KB)
#define PANEL3_SH ((size_t)(256 * 256 * 8))   // shorts per w3 256-col panel (1MB)
#define XBLK_SH   ((size_t)(128 * 128 * 8))   // shorts per 128-row Xg block (256KB)
#define HBLK_SH   ((size_t)(256 * 128 * 8))   // shorts per 128-row Hsw block (512KB)

typedef __attribute__((ext_vector_type(8))) short short8;
typedef __attribute__((ext_vector_type(4))) float f32x4;
typedef unsigned short us;

__device__ __forceinline__ us f2bf(float f) {
    unsigned int u = __builtin_bit_cast(unsigned int, f);
    unsigned int r = (u + 0x7fffu + ((u >> 16) & 1u)) >> 16;   // RNE
    return (us)r;
}

__device__ __forceinline__ void gl_lds16(const us* g, us* l) {
    __builtin_amdgcn_global_load_lds(
        (const __attribute__((address_space(1))) void*)g,
        (__attribute__((address_space(3))) void*)l, 16, 0, 0);
}

#define VMW4 asm volatile("s_waitcnt vmcnt(4)" ::: "memory")
#define VMW0 asm volatile("s_waitcnt vmcnt(0)" ::: "memory")
#define BARM asm volatile("s_barrier" ::: "memory")
#define PRIO1 __builtin_amdgcn_s_setprio(1)
#define PRIO0 __builtin_amdgcn_s_setprio(0)

// ---------------- gating phase A: logits/softmax/top2, NO global atomics ----------------
__global__ __launch_bounds__(256) void gate_compute(
    const float* __restrict__ x, const float* __restrict__ gw, const float* __restrict__ gb,
    int* __restrict__ sel, float2* __restrict__ wpair, float* __restrict__ usage_part)
{
    const int lane = threadIdx.x & 63;
    const int tok = blockIdx.x * 4 + (threadIdx.x >> 6);

    __shared__ float su[NE];
    if (threadIdx.x < NE) su[threadIdx.x] = 0.f;
    __syncthreads();

    float acc[NE];
#pragma unroll
    for (int e = 0; e < NE; e++) acc[e] = 0.f;

    const float* xr = x + (size_t)tok * DIM;
    for (int d = lane; d < DIM; d += 64) {
        float xv = xr[d];
        const float4* g4 = (const float4*)(gw + (size_t)d * NE);
        float4 ga = g4[0], gc = g4[1];
        acc[0] = fmaf(xv, ga.x, acc[0]);
        acc[1] = fmaf(xv, ga.y, acc[1]);
        acc[2] = fmaf(xv, ga.z, acc[2]);
        acc[3] = fmaf(xv, ga.w, acc[3]);
        acc[4] = fmaf(xv, gc.x, acc[4]);
        acc[5] = fmaf(xv, gc.y, acc[5]);
        acc[6] = fmaf(xv, gc.z, acc[6]);
        acc[7] = fmaf(xv, gc.w, acc[7]);
    }
#pragma unroll
    for (int e = 0; e < NE; e++) {
#pragma unroll
        for (int off = 32; off > 0; off >>= 1)
            acc[e] += __shfl_xor(acc[e], off);
    }

    if (lane == 0) {
        float lg[NE], p[NE];
        float mx = -1e30f;
#pragma unroll
        for (int e = 0; e < NE; e++) { lg[e] = acc[e] + gb[e]; mx = fmaxf(mx, lg[e]); }
        float s = 0.f;
#pragma unroll
        for (int e = 0; e < NE; e++) { p[e] = __expf(lg[e] - mx); s += p[e]; }
        float inv = 1.f / s;
#pragma unroll
        for (int e = 0; e < NE; e++) p[e] *= inv;
#pragma unroll
        for (int e = 0; e < NE; e++) atomicAdd(&su[e], p[e]);   // LDS atomic only

        int e1 = 0; float v1 = p[0];
#pragma unroll
        for (int e = 1; e < NE; e++) if (p[e] > v1) { v1 = p[e]; e1 = e; }
        int e2 = -1; float v2 = -1e30f;
#pragma unroll
        for (int e = 0; e < NE; e++) if (e != e1 && p[e] > v2) { v2 = p[e]; e2 = e; }

        sel[tok] = e1 | (e2 << 4);
        wpair[tok] = make_float2(v1, v2);
    }
    __syncthreads();
    if (threadIdx.x < NE) usage_part[blockIdx.x * NE + threadIdx.x] = su[threadIdx.x];
}

// ---------------- gating phase B: deterministic counting-sort, one block per expert ----------------
__global__ __launch_bounds__(256) void scan_kernel(
    const int* __restrict__ sel, const float2* __restrict__ wpair,
    int* __restrict__ counts, int* __restrict__ lists, float* __restrict__ wlist)
{
    const int e = blockIdx.x;
    const int t = threadIdx.x;
    const int base_tok = t * 32;

    unsigned selm = 0, km = 0;
#pragma unroll
    for (int i = 0; i < 32; i++) {
        int s = sel[base_tok + i];
        int e1 = s & 15, e2 = (s >> 4) & 15;
        if (e1 == e) selm |= (1u << i);
        else if (e2 == e) { selm |= (1u << i); km |= (1u << i); }
    }
    const int myc = __popc(selm);

    __shared__ int tot[256];
    tot[t] = myc;
    __syncthreads();
#pragma unroll
    for (int d = 1; d < 256; d <<= 1) {
        int v = (t >= d) ? tot[t - d] : 0;
        __syncthreads();
        tot[t] += v;
        __syncthreads();
    }
    int pos = tot[t] - myc;          // exclusive prefix
    if (t == 255) counts[e] = tot[255];

    for (int i = 0; i < 32; i++) {
        if (selm & (1u << i)) {
            int tok = base_tok + i;
            int k = (km >> i) & 1;
            lists[e * N_TOK + pos] = tok * 2 + k;
            float2 wp = wpair[tok];
            wlist[e * N_TOK + pos] = k ? wp.y : wp.x;
            pos++;
        }
    }
}

// usage[e] = deterministic tree-sum of 2048 per-block partials
__global__ __launch_bounds__(256) void usage_reduce(
    const float* __restrict__ part, float* __restrict__ usage)
{
    const int t = threadIdx.x;
    const int e = t & 7, chunk = t >> 3;   // 32 chunks
    float s = 0.f;
    for (int b = chunk; b < 2048; b += 32) s += part[b * NE + e];
    __shared__ float red[256];
    red[t] = s;
    __syncthreads();
#pragma unroll
    for (int step = 128; step >= 8; step >>= 1) {
        if (t < step) red[t] += red[t + step];
        __syncthreads();
    }
    if (t < NE) usage[t] = red[t];
}

__global__ void loss_kernel(const float* __restrict__ usage, float* __restrict__ out_loss)
{
    if (threadIdx.x == 0) {
        float l = 0.f;
        for (int e = 0; e < NE; e++) {
            float u = usage[e] / (float)N_TOK;
            l += u * logf(u + 1e-9f);
        }
        *out_loss = l;
    }
}

// exact prefix + dense (e, m0) tile worklist
__global__ void prefix_kernel(const int* __restrict__ counts,
                              int* __restrict__ base_exact, int* __restrict__ ntiles,
                              int* __restrict__ tmap_e, int* __restrict__ tmap_m0)
{
    if (threadIdx.x == 0) {
        int bx = 0, nt = 0;
        for (int e = 0; e < NE; e++) {
            base_exact[e] = bx;
            for (int m0 = 0; m0 < counts[e]; m0 += 256) {
                tmap_e[nt] = e; tmap_m0[nt] = m0; nt++;
            }
            bx += counts[e];
        }
        ntiles[0] = nt;
    }
}

// inv[rid] = global list position of routing entry rid
__global__ __launch_bounds__(256) void inv_kernel(
    const int* __restrict__ counts, const int* __restrict__ lists,
    const int* __restrict__ base_exact, int* __restrict__ inv)
{
    const int e = blockIdx.y;
    const int idx = blockIdx.x * 256 + threadIdx.x;
    if (idx < counts[e]) inv[lists[e * N_TOK + idx]] = base_exact[e] + idx;
}

// ---------------- X pre-gather: x -> Xg (bf16, routing order, chunk-tiled) ----------------
__global__ __launch_bounds__(256) void xgather_kernel(
    const float* __restrict__ x,
    const int* __restrict__ counts, const int* __restrict__ lists,
    const int* __restrict__ base_exact,
    us* __restrict__ Xg)
{
    __shared__ int toks[128];
    __shared__ int bexs[NE], cnts[NE];
    const int t = threadIdx.x;
    if (t < NE) { bexs[t] = base_exact[t]; cnts[t] = counts[t]; }
    __syncthreads();
    if (t < 128) {
        int gpos = blockIdx.x * 128 + t;
        int e = 0;
#pragma unroll
        for (int k = 1; k < NE; k++) if (gpos >= bexs[k]) e = k;
        int idx = gpos - bexs[e];
        int tok = (idx < cnts[e]) ? (lists[e * N_TOK + idx] >> 1) : 0;
        toks[t] = tok;
    }
    __syncthreads();

    us* op = Xg + (size_t)blockIdx.x * XBLK_SH;
    const int rr = t & 127;
    const int ch = t >> 7;
    const int tok = toks[rr];
#pragma unroll
    for (int it = 0; it < 64; it++) {
        int c = it * 2 + ch;
        const float4* src = (const float4*)(x + (size_t)tok * DIM + c * 8);
        float4 a = src[0], b = src[1];
        short8 v;
        v[0] = (short)f2bf(a.x); v[1] = (short)f2bf(a.y);
        v[2] = (short)f2bf(a.z); v[3] = (short)f2bf(a.w);
        v[4] = (short)f2bf(b.x); v[5] = (short)f2bf(b.y);
        v[6] = (short)f2bf(b.z); v[7] = (short)f2bf(b.w);
        *(short8*)(op + (size_t)(c * 128 + rr) * 8) = v;
    }
}

// ---------------- w1,w2 -> [e][nbx16][g128][row256][8], rows = [W1 128 | W2 128] ----------------
__global__ __launch_bounds__(256) void wswz12_kernel(
    const float* __restrict__ w1, const float* __restrict__ w2, us* __restrict__ out)
{
    const int e = blockIdx.z, nbx = blockIdx.y, gs = blockIdx.x;
    us* op = out + ((size_t)e * NB1 + nbx) * PANEL1_SH + (size_t)gs * 8 * 256 * 8;
    const float* w1e = w1 + (size_t)e * DIM * HID;
    const float* w2e = w2 + (size_t)e * DIM * HID;
    const int t = threadIdx.x;
#pragma unroll
    for (int it = 0; it < 8; it++) {
        int idx = it * 256 + t;
        int g = idx >> 8, row = idx & 255;
        int col = nbx * 128 + (row & 127);
        const float* src = (row < 128 ? w1e : w2e) + (size_t)((gs * 8 + g) * 8) * HID + col;
        short8 v;
#pragma unroll
        for (int s = 0; s < 8; s++) v[s] = (short)f2bf(src[(size_t)s * HID]);
        *(short8*)(op + (size_t)idx * 8) = v;
    }
}

// ---------------- w3 -> [e][nbx4][g256][row256][8] ----------------
__global__ __launch_bounds__(256) void wswz3_kernel(
    const float* __restrict__ w3, us* __restrict__ out)
{
    const int e = blockIdx.z, nbx = blockIdx.y, gs = blockIdx.x;
    us* op = out + ((size_t)e * NB2 + nbx) * PANEL3_SH + (size_t)gs * 8 * 256 * 8;
    const float* w3e = w3 + (size_t)e * HID * DIM;
    const int t = threadIdx.x;
#pragma unroll
    for (int it = 0; it < 8; it++) {
        int idx = it * 256 + t;
        int g = idx >> 8, row = idx & 255;
        int col = nbx * 256 + row;
        const float* src = w3e + (size_t)((gs * 8 + g) * 8) * DIM + col;
        short8 v;
#pragma unroll
        for (int s = 0; s < 8; s++) v[s] = (short)f2bf(src[(size_t)s * DIM]);
        *(short8*)(op + (size_t)idx * 8) = v;
    }
}

#define ABUF(b) ((us*)(SM + (b)*32768))
#define BBUF(b) ((us*)(SM + 65536 + (b)*32768))

#define AF_READ(b, h) do {                                               \
    _Pragma("unroll")                                                    \
    for (int mi = 0; mi < 8; mi++)                                       \
        af[mi] = *(const short8*)(ABUF(b) + ((h)*1024 + kc*256 + Mw + mi*16 + fr)*8); \
} while (0)
#define BF_READ(b, h, nh) do {                                           \
    bf[0] = *(const short8*)(BBUF(b) + ((h)*1024 + kc*256 + Nw + (nh)*32 + fr)*8); \
    bf[1] = *(const short8*)(BBUF(b) + ((h)*1024 + kc*256 + Nw + (nh)*32 + 16 + fr)*8); \
} while (0)
#define CLUST(nh) do {                                                   \
    PRIO1;                                                               \
    _Pragma("unroll")                                                    \
    for (int ni = 0; ni < 2; ni++) {                                     \
        _Pragma("unroll")                                                \
        for (int mi = 0; mi < 8; mi++)                                   \
            acc[mi][(nh)*2 + ni] = __builtin_amdgcn_mfma_f32_16x16x32_bf16( \
                af[mi], bf[ni], acc[mi][(nh)*2 + ni], 0, 0, 0);          \
    }                                                                    \
    PRIO0;                                                               \
} while (0)

// ---------------- pass A: Xg @ [W1|W2] -> swiglu -> Hsw ----------------
__global__ __launch_bounds__(512, 2) void ffn1_mfma_kernel(
    const us* __restrict__ Xg, const us* __restrict__ W12sw,
    const float* __restrict__ b1, const float* __restrict__ b2,
    const int* __restrict__ counts, const int* __restrict__ base_exact,
    const int* __restrict__ ntiles, const int* __restrict__ tmap_e, const int* __restrict__ tmap_m0,
    us* __restrict__ Hsw)
{
    const int by = blockIdx.y;
    if (by >= ntiles[0]) return;
    const int e  = tmap_e[by];
    const int m0 = tmap_m0[by];
    const int cnt = counts[e];
    const int bex = base_exact[e];
    const int nbx = blockIdx.x;

    __shared__ __align__(16) unsigned char SM[132096];

    const int t = threadIdx.x;
    const int lane = t & 63, wv = t >> 6;
    const int wr = wv >> 2, wc = wv & 3;
    const int Mw = wr * 128, Nw = wc * 64;
    const int fr = lane & 15, kc = lane >> 4;

    float bb[4];
    {
        const float* bsrc = (wc < 2) ? b1 : b2;
#pragma unroll
        for (int ni = 0; ni < 4; ni++)
            bb[ni] = bsrc[e * HID + nbx * 128 + (wc & 1) * 64 + ni * 16 + fr];
    }
    __syncthreads();

    const int c0 = wv * 128 + lane;
    const int c1 = c0 + 64;
    const int RA0 = min(bex + m0 + (c0 & 255), N_TOK * 2 - 1);
    const int RA1 = min(bex + m0 + (c1 & 255), N_TOK * 2 - 1);
    const us* ApA = Xg + (size_t)(RA0 >> 7) * XBLK_SH + (size_t)(c0 >> 8) * 1024 + (RA0 & 127) * 8;
    const us* ApB = Xg + (size_t)(RA1 >> 7) * XBLK_SH + (size_t)(c1 >> 8) * 1024 + (RA1 & 127) * 8;
    const us* Wp = W12sw + ((size_t)e * NB1 + nbx) * PANEL1_SH;
    const int dbase = wv * 128 * 8;

    f32x4 acc[8][4];
    const f32x4 fz = {0.f, 0.f, 0.f, 0.f};
#pragma unroll
    for (int i = 0; i < 8; i++)
#pragma unroll
        for (int j = 0; j < 4; j++) acc[i][j] = fz;

    #define STAGE_A(b, tile, h) do {                                             \
        gl_lds16(ApA + (size_t)((tile)*8 + (h)*4) * 1024, ABUF(b) + ((h)*1024)*8 + dbase); \
        gl_lds16(ApB + (size_t)((tile)*8 + (h)*4) * 1024, ABUF(b) + ((h)*1024 + 64)*8 + dbase); \
    } while (0)
    #define STAGE_B(b, tile, h) do {                                             \
        const us* s_ = Wp + ((size_t)(tile)*2048 + (h)*1024) * 8;                \
        gl_lds16(s_ + (size_t)c0 * 8, BBUF(b) + ((h)*1024)*8 + dbase);           \
        gl_lds16(s_ + (size_t)c1 * 8, BBUF(b) + ((h)*1024 + 64)*8 + dbase);      \
    } while (0)

    short8 af[8], bf[2];

    STAGE_A(0, 0, 0); STAGE_B(0, 0, 0); STAGE_A(0, 0, 1); STAGE_B(0, 0, 1);
    VMW4; BARM;

    for (int tl = 0; tl < NT1; ++tl) {
        const int b = tl & 1, nb = b ^ 1;
        const bool more = (tl + 1 < NT1);
        AF_READ(b, 0); BF_READ(b, 0, 0);
        if (more) STAGE_A(nb, tl + 1, 0);
        BARM; CLUST(0); BARM;
        BF_READ(b, 0, 1);
        if (more) { STAGE_B(nb, tl + 1, 0); VMW4; } else { VMW0; }
        BARM; CLUST(1); BARM;
        AF_READ(b, 1); BF_READ(b, 1, 0);
        if (more) STAGE_A(nb, tl + 1, 1);
        BARM; CLUST(0); BARM;
        BF_READ(b, 1, 1);
        if (more) { STAGE_B(nb, tl + 1, 1); VMW4; }
        BARM; CLUST(1); BARM;
    }
    #undef STAGE_A
    #undef STAGE_B

    // ---- SwiGLU epilogue via LDS gate exchange ----
    float* G = (float*)SM;
    if (wc >= 2) {
        const int cp = wc - 2;
#pragma unroll
        for (int ni = 0; ni < 4; ni++) {
            int c2 = cp * 64 + ni * 16 + fr;
#pragma unroll
            for (int mi = 0; mi < 8; mi++) {
#pragma unroll
                for (int j = 0; j < 4; j++) {
                    int m = mi * 16 + kc * 4 + j;
                    float g = 1.f / (1.f + __expf(-(acc[mi][ni][j] + bb[ni])));
                    G[(wr * 128 + c2) * 129 + m] = g;
                }
            }
        }
    }
    __syncthreads();
    if (wc < 2) {
#pragma unroll
        for (int ni = 0; ni < 4; ni++) {
            int c2 = wc * 64 + ni * 16 + fr;
            int ch = nbx * 128 + c2;
            size_t cb = (size_t)(ch >> 3) * 128 * 8 + (ch & 7);
#pragma unroll
            for (int mi = 0; mi < 8; mi++) {
#pragma unroll
                for (int j = 0; j < 4; j++) {
                    int m = mi * 16 + kc * 4 + j;
                    int rl = wr * 128 + m;
                    if (m0 + rl >= cnt) continue;
                    float h = (acc[mi][ni][j] + bb[ni]) * G[(wr * 128 + c2) * 129 + m];
                    int R = bex + m0 + rl;
                    Hsw[(size_t)(R >> 7) * HBLK_SH + cb + (size_t)(R & 127) * 8] = f2bf(h);
                }
            }
        }
    }
}

// ---------------- pass B: Hsw @ w3 -> f32 partials P ----------------
__global__ __launch_bounds__(512, 2) void ffn2_mfma_kernel(
    const us* __restrict__ Hsw, const us* __restrict__ W3sw, const float* __restrict__ b3,
    const int* __restrict__ counts, const int* __restrict__ base_exact,
    const int* __restrict__ ntiles, const int* __restrict__ tmap_e, const int* __restrict__ tmap_m0,
    const float* __restrict__ wts,
    float* __restrict__ P, int pan0)
{
    const int by = blockIdx.y;
    if (by >= ntiles[0]) return;
    const int e  = tmap_e[by];
    const int m0 = tmap_m0[by];
    const int cnt = counts[e];
    const int bex = base_exact[e];
    const int nbx = pan0 + blockIdx.x;

    __shared__ __align__(16) unsigned char SM[132096];
    float* rowwt = (float*)(SM + 131072);

    const int t = threadIdx.x;
    if (t < 256) {
        int idx = m0 + t;
        rowwt[t] = (idx < cnt) ? wts[e * N_TOK + idx] : 0.f;
    }

    const int lane = t & 63, wv = t >> 6;
    const int wr = wv >> 2, wc = wv & 3;
    const int Mw = wr * 128, Nw = wc * 64;
    const int fr = lane & 15, kc = lane >> 4;

    float bb3[4];
#pragma unroll
    for (int ni = 0; ni < 4; ni++)
        bb3[ni] = b3[e * DIM + nbx * 256 + wc * 64 + ni * 16 + fr];
    __syncthreads();

    const int c0 = wv * 128 + lane;
    const int c1 = c0 + 64;
    const int RA0 = min(bex + m0 + (c0 & 255), N_TOK * 2 - 1);
    const int RA1 = min(bex + m0 + (c1 & 255), N_TOK * 2 - 1);
    const us* HpA = Hsw + (size_t)(RA0 >> 7) * HBLK_SH + (size_t)(c0 >> 8) * 1024 + (RA0 & 127) * 8;
    const us* HpB = Hsw + (size_t)(RA1 >> 7) * HBLK_SH + (size_t)(c1 >> 8) * 1024 + (RA1 & 127) * 8;
    const us* Wp = W3sw + ((size_t)e * NB2 + nbx) * PANEL3_SH;
    const int dbase = wv * 128 * 8;

    f32x4 acc[8][4];
    const f32x4 fz = {0.f, 0.f, 0.f, 0.f};
#pragma unroll
    for (int i = 0; i < 8; i++)
#pragma unroll
        for (int j = 0; j < 4; j++) acc[i][j] = fz;

    #define STAGE_A2(b, tile, h) do {                                            \
        gl_lds16(HpA + (size_t)((tile)*8 + (h)*4) * 1024, ABUF(b) + ((h)*1024)*8 + dbase); \
        gl_lds16(HpB + (size_t)((tile)*8 + (h)*4) * 1024, ABUF(b) + ((h)*1024 + 64)*8 + dbase); \
    } while (0)
    #define STAGE_B2(b, tile, h) do {                                            \
        const us* s_ = Wp + ((size_t)(tile)*2048 + (h)*1024) * 8;                \
        gl_lds16(s_ + (size_t)c0 * 8, BBUF(b) + ((h)*1024)*8 + dbase);           \
        gl_lds16(s_ + (size_t)c1 * 8, BBUF(b) + ((h)*1024 + 64)*8 + dbase);      \
    } while (0)

    short8 af[8], bf[2];

    STAGE_A2(0, 0, 0); STAGE_B2(0, 0, 0); STAGE_A2(0, 0, 1); STAGE_B2(0, 0, 1);
    VMW4; BARM;

    for (int tl = 0; tl < NT2; ++tl) {
        const int b = tl & 1, nb = b ^ 1;
        const bool more = (tl + 1 < NT2);
        AF_READ(b, 0); BF_READ(b, 0, 0);
        if (more) STAGE_A2(nb, tl + 1, 0);
        BARM; CLUST(0); BARM;
        BF_READ(b, 0, 1);
        if (more) { STAGE_B2(nb, tl + 1, 0); VMW4; } else { VMW0; }
        BARM; CLUST(1); BARM;
        AF_READ(b, 1); BF_READ(b, 1, 0);
        if (more) STAGE_A2(nb, tl + 1, 1);
        BARM; CLUST(0); BARM;
        BF_READ(b, 1, 1);
        if (more) { STAGE_B2(nb, tl + 1, 1); VMW4; }
        BARM; CLUST(1); BARM;
    }
    #undef STAGE_A2
    #undef STAGE_B2

#pragma unroll
    for (int ni = 0; ni < 4; ni++) {
        int cp = blockIdx.x * 256 + wc * 64 + ni * 16 + fr;
#pragma unroll
        for (int mi = 0; mi < 8; mi++) {
#pragma unroll
            for (int j = 0; j < 4; j++) {
                int rl = wr * 128 + mi * 16 + kc * 4 + j;
                if (m0 + rl >= cnt) continue;
                float v = (acc[mi][ni][j] + bb3[ni]) * rowwt[rl];
                P[(size_t)(bex + m0 + rl) * 512 + cp] = v;
            }
        }
    }
}

// out[tok][colbase + c] = P[inv[2t]][c] + P[inv[2t+1]][c]
__global__ __launch_bounds__(256) void combine_kernel(
    const float* __restrict__ P, const int* __restrict__ inv,
    float* __restrict__ out, int colbase)
{
    int gid = blockIdx.x * 256 + threadIdx.x;
    int tok = gid >> 7;
    int c4 = (gid & 127) * 4;
    const float4 a = *(const float4*)(P + (size_t)inv[tok * 2] * 512 + c4);
    const float4 b = *(const float4*)(P + (size_t)inv[tok * 2 + 1] * 512 + c4);
    float4 r = make_float4(a.x + b.x, a.y + b.y, a.z + b.z, a.w + b.w);
    *(float4*)(out + (size_t)tok * DIM + colbase + c4) = r;
}

extern "C" void kernel_launch(void* const* d_in, const int* in_sizes, int n_in,
                              void* d_out, int out_size, void* d_ws, size_t ws_size,
                              hipStream_t stream) {
    (void)in_sizes; (void)n_in; (void)out_size; (void)ws_size;
    const float* x      = (const float*)d_in[0];
    const float* gate_w = (const float*)d_in[1];
    const float* gate_b = (const float*)d_in[2];
    const float* w1     = (const float*)d_in[3];
    const float* b1     = (const float*)d_in[4];
    const float* w2     = (const float*)d_in[5];
    const float* b2     = (const float*)d_in[6];
    const float* w3     = (const float*)d_in[7];
    const float* b3     = (const float*)d_in[8];
    float* out = (float*)d_out;

    char* ws = (char*)d_ws;
    float* usage      = (float*)ws;                               // @0, 32 B
    int*   counts     = (int*)(ws + 32);                          // @32, 32 B
    int*   base_exact = (int*)(ws + 64);                          // @64, 32 B
    int*   ntiles     = (int*)(ws + 96);                          // @96, 16 B
    int*   tmap_e     = (int*)(ws + 128);                         // 512 B
    int*   tmap_m0    = (int*)(ws + 640);                         // 512 B
    int*   lists      = (int*)(ws + 4096);                        // 256 KB
    float* wts        = (float*)(ws + 4096 + (size_t)NE * N_TOK * 4);   // 256 KB
    int*   inv        = (int*)(ws + 4096 + (size_t)2 * NE * N_TOK * 4); // 64 KB
    int*   sel        = (int*)(ws + 4096 + 576 * 1024);           // 32 KB
    float2* wpair     = (float2*)(ws + 4096 + 608 * 1024);        // 64 KB
    float* usage_part = (float*)(ws + 4096 + 672 * 1024);         // 64 KB
    us* Hsw   = (us*)(ws + (1ull  << 20));                        // @1 MiB, 64 MiB
    us* W12sw = (us*)(ws + (65ull << 20));                        // @65 MiB, 64 MiB (ffn1 phase)
    us* W3sw  = W12sw;                                            // @65 MiB, 32 MiB (ffn2 phase)
    float* P  = (float*)(ws + (97ull << 20));                     // @97 MiB, 32 MiB (ffn2 phase)
    us* Xg    = (us*)d_out;                                       // 32 MiB, routing-order X

    gate_compute<<<N_TOK / 4, 256, 0, stream>>>(x, gate_w, gate_b, sel, wpair, usage_part);
    scan_kernel<<<NE, 256, 0, stream>>>(sel, wpair, counts, lists, wts);
    usage_reduce<<<1, 256, 0, stream>>>(usage_part, usage);
    prefix_kernel<<<1, 64, 0, stream>>>(counts, base_exact, ntiles, tmap_e, tmap_m0);
    {
        dim3 gI(N_TOK / 256, NE);
        inv_kernel<<<gI, 256, 0, stream>>>(counts, lists, base_exact, inv);
    }
    xgather_kernel<<<N_TOK * 2 / 128, 256, 0, stream>>>(x, counts, lists, base_exact, Xg);

    dim3 gW12(16, NB1, NE);
    wswz12_kernel<<<gW12, 256, 0, stream>>>(w1, w2, W12sw);

    dim3 gA(NB1, MAXT, 1);
    ffn1_mfma_kernel<<<gA, 512, 0, stream>>>(Xg, W12sw, b1, b2, counts, base_exact,
                                             ntiles, tmap_e, tmap_m0, Hsw);

    loss_kernel<<<1, 64, 0, stream>>>(usage, out + (size_t)N_TOK * DIM);

    dim3 gW3(32, NB2, NE);
    wswz3_kernel<<<gW3, 256, 0, stream>>>(w3, W3sw);

    dim3 gB(2, MAXT, 1);
    ffn2_mfma_kernel<<<gB, 512, 0, stream>>>(Hsw, W3sw, b3, counts, base_exact,
                                             ntiles, tmap_e, tmap_m0, wts, P, 0);
    combine_kernel<<<N_TOK * 128 / 256, 256, 0, stream>>>(P, inv, out, 0);
    ffn2_mfma_kernel<<<gB, 512, 0, stream>>>(Hsw, W3sw, b3, counts, base_exact,
                                             ntiles, tmap_e, tmap_m0, wts, P, 2);
    combine_kernel<<<N_TOK * 128 / 256, 256, 0, stream>>>(P, inv, out, 512);
}

// Round 14
// 496.097 us; speedup vs baseline: 1.4457x; 1.0114x over previous
//
#include <hip/hip_runtime.h>
#include <hip/hip_bf16.h>
#include <math.h>

#define N_TOK 8192
#define DIM   1024
#define HID   2048
#define NE    8
#define NT1   16     // DIM/64 K-tiles (ffn1)
#define NT2   32     // HID/64 K-tiles (ffn2)
#define NB1   16     // HID/128 panels (ffn1)
#define NB2   4      // DIM/256 panels (ffn2)
#define MAXT  72     // max (e,m0) tiles
#define PANEL1_SH ((size_t)(128 * 256 * 8))   // shorts per ffn1 [W1|W2] panel (512KB)
#define PANEL3_SH ((size_t)(256 * 256 * 8))   // shorts per w3 256-col panel (1MB)
#define XBLK_SH   ((size_t)(128 * 128 * 8))   // shorts per 128-row Xg block (256KB)
#define HBLK_SH   ((size_t)(256 * 128 * 8))   // shorts per 128-row Hsw block (512KB)

typedef __attribute__((ext_vector_type(8))) short short8;
typedef __attribute__((ext_vector_type(4))) float f32x4;
typedef unsigned short us;

__device__ __forceinline__ us f2bf(float f) {
    unsigned int u = __builtin_bit_cast(unsigned int, f);
    unsigned int r = (u + 0x7fffu + ((u >> 16) & 1u)) >> 16;   // RNE
    return (us)r;
}

__device__ __forceinline__ void gl_lds16(const us* g, us* l) {
    __builtin_amdgcn_global_load_lds(
        (const __attribute__((address_space(1))) void*)g,
        (__attribute__((address_space(3))) void*)l, 16, 0, 0);
}

#define VMW4 asm volatile("s_waitcnt vmcnt(4)" ::: "memory")
#define VMW0 asm volatile("s_waitcnt vmcnt(0)" ::: "memory")
#define BARM asm volatile("s_barrier" ::: "memory")
#define PRIO1 __builtin_amdgcn_s_setprio(1)
#define PRIO0 __builtin_amdgcn_s_setprio(0)

// ---------------- gating phase A: logits/softmax/top2, NO global atomics ----------------
__global__ __launch_bounds__(256) void gate_compute(
    const float* __restrict__ x, const float* __restrict__ gw, const float* __restrict__ gb,
    int* __restrict__ sel, float2* __restrict__ wpair, float* __restrict__ usage_part)
{
    const int lane = threadIdx.x & 63;
    const int tok = blockIdx.x * 4 + (threadIdx.x >> 6);

    __shared__ float su[NE];
    if (threadIdx.x < NE) su[threadIdx.x] = 0.f;
    __syncthreads();

    float acc[NE];
#pragma unroll
    for (int e = 0; e < NE; e++) acc[e] = 0.f;

    const float* xr = x + (size_t)tok * DIM;
    for (int d = lane; d < DIM; d += 64) {
        float xv = xr[d];
        const float4* g4 = (const float4*)(gw + (size_t)d * NE);
        float4 ga = g4[0], gc = g4[1];
        acc[0] = fmaf(xv, ga.x, acc[0]);
        acc[1] = fmaf(xv, ga.y, acc[1]);
        acc[2] = fmaf(xv, ga.z, acc[2]);
        acc[3] = fmaf(xv, ga.w, acc[3]);
        acc[4] = fmaf(xv, gc.x, acc[4]);
        acc[5] = fmaf(xv, gc.y, acc[5]);
        acc[6] = fmaf(xv, gc.z, acc[6]);
        acc[7] = fmaf(xv, gc.w, acc[7]);
    }
#pragma unroll
    for (int e = 0; e < NE; e++) {
#pragma unroll
        for (int off = 32; off > 0; off >>= 1)
            acc[e] += __shfl_xor(acc[e], off);
    }

    if (lane == 0) {
        float lg[NE], p[NE];
        float mx = -1e30f;
#pragma unroll
        for (int e = 0; e < NE; e++) { lg[e] = acc[e] + gb[e]; mx = fmaxf(mx, lg[e]); }
        float s = 0.f;
#pragma unroll
        for (int e = 0; e < NE; e++) { p[e] = __expf(lg[e] - mx); s += p[e]; }
        float inv = 1.f / s;
#pragma unroll
        for (int e = 0; e < NE; e++) p[e] *= inv;
#pragma unroll
        for (int e = 0; e < NE; e++) atomicAdd(&su[e], p[e]);   // LDS atomic only

        int e1 = 0; float v1 = p[0];
#pragma unroll
        for (int e = 1; e < NE; e++) if (p[e] > v1) { v1 = p[e]; e1 = e; }
        int e2 = -1; float v2 = -1e30f;
#pragma unroll
        for (int e = 0; e < NE; e++) if (e != e1 && p[e] > v2) { v2 = p[e]; e2 = e; }

        sel[tok] = e1 | (e2 << 4);
        wpair[tok] = make_float2(v1, v2);
    }
    __syncthreads();
    if (threadIdx.x < NE) usage_part[blockIdx.x * NE + threadIdx.x] = su[threadIdx.x];
}

// ---------------- gating phase B: deterministic counting-sort, one block per expert ----------------
__global__ __launch_bounds__(256) void scan_kernel(
    const int* __restrict__ sel, const float2* __restrict__ wpair,
    int* __restrict__ counts, int* __restrict__ lists, float* __restrict__ wlist)
{
    const int e = blockIdx.x;
    const int t = threadIdx.x;
    const int base_tok = t * 32;

    unsigned selm = 0, km = 0;
#pragma unroll
    for (int i = 0; i < 32; i++) {
        int s = sel[base_tok + i];
        int e1 = s & 15, e2 = (s >> 4) & 15;
        if (e1 == e) selm |= (1u << i);
        else if (e2 == e) { selm |= (1u << i); km |= (1u << i); }
    }
    const int myc = __popc(selm);

    __shared__ int tot[256];
    tot[t] = myc;
    __syncthreads();
#pragma unroll
    for (int d = 1; d < 256; d <<= 1) {
        int v = (t >= d) ? tot[t - d] : 0;
        __syncthreads();
        tot[t] += v;
        __syncthreads();
    }
    int pos = tot[t] - myc;          // exclusive prefix
    if (t == 255) counts[e] = tot[255];

    for (int i = 0; i < 32; i++) {
        if (selm & (1u << i)) {
            int tok = base_tok + i;
            int k = (km >> i) & 1;
            lists[e * N_TOK + pos] = tok * 2 + k;
            float2 wp = wpair[tok];
            wlist[e * N_TOK + pos] = k ? wp.y : wp.x;
            pos++;
        }
    }
}

// usage[e] = deterministic tree-sum of 2048 per-block partials
__global__ __launch_bounds__(256) void usage_reduce(
    const float* __restrict__ part, float* __restrict__ usage)
{
    const int t = threadIdx.x;
    const int e = t & 7, chunk = t >> 3;
    float s = 0.f;
    for (int b = chunk; b < 2048; b += 32) s += part[b * NE + e];
    __shared__ float red[256];
    red[t] = s;
    __syncthreads();
#pragma unroll
    for (int step = 128; step >= 8; step >>= 1) {
        if (t < step) red[t] += red[t + step];
        __syncthreads();
    }
    if (t < NE) usage[t] = red[t];
}

__global__ void loss_kernel(const float* __restrict__ usage, float* __restrict__ out_loss)
{
    if (threadIdx.x == 0) {
        float l = 0.f;
        for (int e = 0; e < NE; e++) {
            float u = usage[e] / (float)N_TOK;
            l += u * logf(u + 1e-9f);
        }
        *out_loss = l;
    }
}

// exact prefix + dense (e, m0) tile worklist
__global__ void prefix_kernel(const int* __restrict__ counts,
                              int* __restrict__ base_exact, int* __restrict__ ntiles,
                              int* __restrict__ tmap_e, int* __restrict__ tmap_m0)
{
    if (threadIdx.x == 0) {
        int bx = 0, nt = 0;
        for (int e = 0; e < NE; e++) {
            base_exact[e] = bx;
            for (int m0 = 0; m0 < counts[e]; m0 += 256) {
                tmap_e[nt] = e; tmap_m0[nt] = m0; nt++;
            }
            bx += counts[e];
        }
        ntiles[0] = nt;
    }
}

// inv[rid] = global list position of routing entry rid
__global__ __launch_bounds__(256) void inv_kernel(
    const int* __restrict__ counts, const int* __restrict__ lists,
    const int* __restrict__ base_exact, int* __restrict__ inv)
{
    const int e = blockIdx.y;
    const int idx = blockIdx.x * 256 + threadIdx.x;
    if (idx < counts[e]) inv[lists[e * N_TOK + idx]] = base_exact[e] + idx;
}

// ---------------- X pre-gather: x -> Xg (bf16, routing order, chunk-tiled) ----------------
__global__ __launch_bounds__(256) void xgather_kernel(
    const float* __restrict__ x,
    const int* __restrict__ counts, const int* __restrict__ lists,
    const int* __restrict__ base_exact,
    us* __restrict__ Xg)
{
    __shared__ int toks[128];
    __shared__ int bexs[NE], cnts[NE];
    const int t = threadIdx.x;
    if (t < NE) { bexs[t] = base_exact[t]; cnts[t] = counts[t]; }
    __syncthreads();
    if (t < 128) {
        int gpos = blockIdx.x * 128 + t;
        int e = 0;
#pragma unroll
        for (int k = 1; k < NE; k++) if (gpos >= bexs[k]) e = k;
        int idx = gpos - bexs[e];
        int tok = (idx < cnts[e]) ? (lists[e * N_TOK + idx] >> 1) : 0;
        toks[t] = tok;
    }
    __syncthreads();

    us* op = Xg + (size_t)blockIdx.x * XBLK_SH;
    const int rr = t & 127;
    const int ch = t >> 7;
    const int tok = toks[rr];
#pragma unroll
    for (int it = 0; it < 64; it++) {
        int c = it * 2 + ch;
        const float4* src = (const float4*)(x + (size_t)tok * DIM + c * 8);
        float4 a = src[0], b = src[1];
        short8 v;
        v[0] = (short)f2bf(a.x); v[1] = (short)f2bf(a.y);
        v[2] = (short)f2bf(a.z); v[3] = (short)f2bf(a.w);
        v[4] = (short)f2bf(b.x); v[5] = (short)f2bf(b.y);
        v[6] = (short)f2bf(b.z); v[7] = (short)f2bf(b.w);
        *(short8*)(op + (size_t)(c * 128 + rr) * 8) = v;
    }
}

// ---------------- w1,w2 -> [e][nbx16][g128][row256][8], rows = [W1 128 | W2 128] ----------------
__global__ __launch_bounds__(256) void wswz12_kernel(
    const float* __restrict__ w1, const float* __restrict__ w2, us* __restrict__ out)
{
    const int e = blockIdx.z, nbx = blockIdx.y, gs = blockIdx.x;
    us* op = out + ((size_t)e * NB1 + nbx) * PANEL1_SH + (size_t)gs * 8 * 256 * 8;
    const float* w1e = w1 + (size_t)e * DIM * HID;
    const float* w2e = w2 + (size_t)e * DIM * HID;
    const int t = threadIdx.x;
#pragma unroll
    for (int it = 0; it < 8; it++) {
        int idx = it * 256 + t;
        int g = idx >> 8, row = idx & 255;
        int col = nbx * 128 + (row & 127);
        const float* src = (row < 128 ? w1e : w2e) + (size_t)((gs * 8 + g) * 8) * HID + col;
        short8 v;
#pragma unroll
        for (int s = 0; s < 8; s++) v[s] = (short)f2bf(src[(size_t)s * HID]);
        *(short8*)(op + (size_t)idx * 8) = v;
    }
}

// ---------------- w3 -> [e][nbx4][g256][row256][8] ----------------
__global__ __launch_bounds__(256) void wswz3_kernel(
    const float* __restrict__ w3, us* __restrict__ out)
{
    const int e = blockIdx.z, nbx = blockIdx.y, gs = blockIdx.x;
    us* op = out + ((size_t)e * NB2 + nbx) * PANEL3_SH + (size_t)gs * 8 * 256 * 8;
    const float* w3e = w3 + (size_t)e * HID * DIM;
    const int t = threadIdx.x;
#pragma unroll
    for (int it = 0; it < 8; it++) {
        int idx = it * 256 + t;
        int g = idx >> 8, row = idx & 255;
        int col = nbx * 256 + row;
        const float* src = w3e + (size_t)((gs * 8 + g) * 8) * DIM + col;
        short8 v;
#pragma unroll
        for (int s = 0; s < 8; s++) v[s] = (short)f2bf(src[(size_t)s * DIM]);
        *(short8*)(op + (size_t)idx * 8) = v;
    }
}

#define ABUF(b) ((us*)(SM + (b)*32768))
#define BBUF(b) ((us*)(SM + 65536 + (b)*32768))

#define AF_READ(b, h) do {                                               \
    _Pragma("unroll")                                                    \
    for (int mi = 0; mi < 8; mi++)                                       \
        af[mi] = *(const short8*)(ABUF(b) + ((h)*1024 + kc*256 + Mw + mi*16 + fr)*8); \
} while (0)
#define BF_READ(b, h, nh) do {                                           \
    bf[0] = *(const short8*)(BBUF(b) + ((h)*1024 + kc*256 + Nw + (nh)*32 + fr)*8); \
    bf[1] = *(const short8*)(BBUF(b) + ((h)*1024 + kc*256 + Nw + (nh)*32 + 16 + fr)*8); \
} while (0)
#define CLUST(nh) do {                                                   \
    PRIO1;                                                               \
    _Pragma("unroll")                                                    \
    for (int ni = 0; ni < 2; ni++) {                                     \
        _Pragma("unroll")                                                \
        for (int mi = 0; mi < 8; mi++)                                   \
            acc[mi][(nh)*2 + ni] = __builtin_amdgcn_mfma_f32_16x16x32_bf16( \
                af[mi], bf[ni], acc[mi][(nh)*2 + ni], 0, 0, 0);          \
    }                                                                    \
    PRIO0;                                                               \
} while (0)

// ---------------- pass A: Xg @ [W1|W2] -> swiglu -> Hsw ----------------
// 1D grid, XCD-aware: hw%8 = XCD; each XCD owns 2 of 16 B-panels (L2-local B).
__global__ __launch_bounds__(512, 2) void ffn1_mfma_kernel(
    const us* __restrict__ Xg, const us* __restrict__ W12sw,
    const float* __restrict__ b1, const float* __restrict__ b2,
    const int* __restrict__ counts, const int* __restrict__ base_exact,
    const int* __restrict__ ntiles, const int* __restrict__ tmap_e, const int* __restrict__ tmap_m0,
    us* __restrict__ Hsw)
{
    const int hw = blockIdx.x;
    const int ix = hw >> 3;                          // 0..2*MAXT-1
    const int nbx = ((hw & 7) << 1) | (ix & 1);      // XCD*2 + sub
    const int by  = ix >> 1;
    if (by >= ntiles[0]) return;
    const int e  = tmap_e[by];
    const int m0 = tmap_m0[by];
    const int cnt = counts[e];
    const int bex = base_exact[e];

    __shared__ __align__(16) unsigned char SM[132096];

    const int t = threadIdx.x;
    const int lane = t & 63, wv = t >> 6;
    const int wr = wv >> 2, wc = wv & 3;
    const int Mw = wr * 128, Nw = wc * 64;
    const int fr = lane & 15, kc = lane >> 4;

    float bb[4];
    {
        const float* bsrc = (wc < 2) ? b1 : b2;
#pragma unroll
        for (int ni = 0; ni < 4; ni++)
            bb[ni] = bsrc[e * HID + nbx * 128 + (wc & 1) * 64 + ni * 16 + fr];
    }
    __syncthreads();

    const int c0 = wv * 128 + lane;
    const int c1 = c0 + 64;
    const int RA0 = min(bex + m0 + (c0 & 255), N_TOK * 2 - 1);
    const int RA1 = min(bex + m0 + (c1 & 255), N_TOK * 2 - 1);
    const us* ApA = Xg + (size_t)(RA0 >> 7) * XBLK_SH + (size_t)(c0 >> 8) * 1024 + (RA0 & 127) * 8;
    const us* ApB = Xg + (size_t)(RA1 >> 7) * XBLK_SH + (size_t)(c1 >> 8) * 1024 + (RA1 & 127) * 8;
    const us* Wp = W12sw + ((size_t)e * NB1 + nbx) * PANEL1_SH;
    const int dbase = wv * 128 * 8;

    f32x4 acc[8][4];
    const f32x4 fz = {0.f, 0.f, 0.f, 0.f};
#pragma unroll
    for (int i = 0; i < 8; i++)
#pragma unroll
        for (int j = 0; j < 4; j++) acc[i][j] = fz;

    #define STAGE_A(b, tile, h) do {                                             \
        gl_lds16(ApA + (size_t)((tile)*8 + (h)*4) * 1024, ABUF(b) + ((h)*1024)*8 + dbase); \
        gl_lds16(ApB + (size_t)((tile)*8 + (h)*4) * 1024, ABUF(b) + ((h)*1024 + 64)*8 + dbase); \
    } while (0)
    #define STAGE_B(b, tile, h) do {                                             \
        const us* s_ = Wp + ((size_t)(tile)*2048 + (h)*1024) * 8;                \
        gl_lds16(s_ + (size_t)c0 * 8, BBUF(b) + ((h)*1024)*8 + dbase);           \
        gl_lds16(s_ + (size_t)c1 * 8, BBUF(b) + ((h)*1024 + 64)*8 + dbase);      \
    } while (0)

    short8 af[8], bf[2];

    STAGE_A(0, 0, 0); STAGE_B(0, 0, 0); STAGE_A(0, 0, 1); STAGE_B(0, 0, 1);
    VMW4; BARM;

    for (int tl = 0; tl < NT1; ++tl) {
        const int b = tl & 1, nb = b ^ 1;
        const bool more = (tl + 1 < NT1);
        AF_READ(b, 0); BF_READ(b, 0, 0);
        if (more) STAGE_A(nb, tl + 1, 0);
        BARM; CLUST(0); BARM;
        BF_READ(b, 0, 1);
        if (more) { STAGE_B(nb, tl + 1, 0); VMW4; } else { VMW0; }
        BARM; CLUST(1); BARM;
        AF_READ(b, 1); BF_READ(b, 1, 0);
        if (more) STAGE_A(nb, tl + 1, 1);
        BARM; CLUST(0); BARM;
        BF_READ(b, 1, 1);
        if (more) { STAGE_B(nb, tl + 1, 1); VMW4; }
        BARM; CLUST(1); BARM;
    }
    #undef STAGE_A
    #undef STAGE_B

    // ---- SwiGLU epilogue via LDS gate exchange ----
    float* G = (float*)SM;
    if (wc >= 2) {
        const int cp = wc - 2;
#pragma unroll
        for (int ni = 0; ni < 4; ni++) {
            int c2 = cp * 64 + ni * 16 + fr;
#pragma unroll
            for (int mi = 0; mi < 8; mi++) {
#pragma unroll
                for (int j = 0; j < 4; j++) {
                    int m = mi * 16 + kc * 4 + j;
                    float g = 1.f / (1.f + __expf(-(acc[mi][ni][j] + bb[ni])));
                    G[(wr * 128 + c2) * 129 + m] = g;
                }
            }
        }
    }
    __syncthreads();
    if (wc < 2) {
#pragma unroll
        for (int ni = 0; ni < 4; ni++) {
            int c2 = wc * 64 + ni * 16 + fr;
            int ch = nbx * 128 + c2;
            size_t cb = (size_t)(ch >> 3) * 128 * 8 + (ch & 7);
#pragma unroll
            for (int mi = 0; mi < 8; mi++) {
#pragma unroll
                for (int j = 0; j < 4; j++) {
                    int m = mi * 16 + kc * 4 + j;
                    int rl = wr * 128 + m;
                    if (m0 + rl >= cnt) continue;
                    float h = (acc[mi][ni][j] + bb[ni]) * G[(wr * 128 + c2) * 129 + m];
                    int R = bex + m0 + rl;
                    Hsw[(size_t)(R >> 7) * HBLK_SH + cb + (size_t)(R & 127) * 8] = f2bf(h);
                }
            }
        }
    }
}

// ---------------- pass B: Hsw @ w3 -> f32 partials P ----------------
// 1D grid per 512-col pass, XCD-aware: XCDs 0-3 -> panel 0, XCDs 4-7 -> panel 1.
__global__ __launch_bounds__(512, 2) void ffn2_mfma_kernel(
    const us* __restrict__ Hsw, const us* __restrict__ W3sw, const float* __restrict__ b3,
    const int* __restrict__ counts, const int* __restrict__ base_exact,
    const int* __restrict__ ntiles, const int* __restrict__ tmap_e, const int* __restrict__ tmap_m0,
    const float* __restrict__ wts,
    float* __restrict__ P, int pan0)
{
    const int hw = blockIdx.x;
    const int xcd = hw & 7;
    const int ix = hw >> 3;                 // 0..MAXT/4-1
    const int pn = xcd >> 2;                // 0/1 panel within pass
    const int by = (ix << 2) | (xcd & 3);
    if (by >= ntiles[0]) return;
    const int e  = tmap_e[by];
    const int m0 = tmap_m0[by];
    const int cnt = counts[e];
    const int bex = base_exact[e];
    const int nbx = pan0 + pn;

    __shared__ __align__(16) unsigned char SM[132096];
    float* rowwt = (float*)(SM + 131072);

    const int t = threadIdx.x;
    if (t < 256) {
        int idx = m0 + t;
        rowwt[t] = (idx < cnt) ? wts[e * N_TOK + idx] : 0.f;
    }

    const int lane = t & 63, wv = t >> 6;
    const int wr = wv >> 2, wc = wv & 3;
    const int Mw = wr * 128, Nw = wc * 64;
    const int fr = lane & 15, kc = lane >> 4;

    float bb3[4];
#pragma unroll
    for (int ni = 0; ni < 4; ni++)
        bb3[ni] = b3[e * DIM + nbx * 256 + wc * 64 + ni * 16 + fr];
    __syncthreads();

    const int c0 = wv * 128 + lane;
    const int c1 = c0 + 64;
    const int RA0 = min(bex + m0 + (c0 & 255), N_TOK * 2 - 1);
    const int RA1 = min(bex + m0 + (c1 & 255), N_TOK * 2 - 1);
    const us* HpA = Hsw + (size_t)(RA0 >> 7) * HBLK_SH + (size_t)(c0 >> 8) * 1024 + (RA0 & 127) * 8;
    const us* HpB = Hsw + (size_t)(RA1 >> 7) * HBLK_SH + (size_t)(c1 >> 8) * 1024 + (RA1 & 127) * 8;
    const us* Wp = W3sw + ((size_t)e * NB2 + nbx) * PANEL3_SH;
    const int dbase = wv * 128 * 8;

    f32x4 acc[8][4];
    const f32x4 fz = {0.f, 0.f, 0.f, 0.f};
#pragma unroll
    for (int i = 0; i < 8; i++)
#pragma unroll
        for (int j = 0; j < 4; j++) acc[i][j] = fz;

    #define STAGE_A2(b, tile, h) do {                                            \
        gl_lds16(HpA + (size_t)((tile)*8 + (h)*4) * 1024, ABUF(b) + ((h)*1024)*8 + dbase); \
        gl_lds16(HpB + (size_t)((tile)*8 + (h)*4) * 1024, ABUF(b) + ((h)*1024 + 64)*8 + dbase); \
    } while (0)
    #define STAGE_B2(b, tile, h) do {                                            \
        const us* s_ = Wp + ((size_t)(tile)*2048 + (h)*1024) * 8;                \
        gl_lds16(s_ + (size_t)c0 * 8, BBUF(b) + ((h)*1024)*8 + dbase);           \
        gl_lds16(s_ + (size_t)c1 * 8, BBUF(b) + ((h)*1024 + 64)*8 + dbase);      \
    } while (0)

    short8 af[8], bf[2];

    STAGE_A2(0, 0, 0); STAGE_B2(0, 0, 0); STAGE_A2(0, 0, 1); STAGE_B2(0, 0, 1);
    VMW4; BARM;

    for (int tl = 0; tl < NT2; ++tl) {
        const int b = tl & 1, nb = b ^ 1;
        const bool more = (tl + 1 < NT2);
        AF_READ(b, 0); BF_READ(b, 0, 0);
        if (more) STAGE_A2(nb, tl + 1, 0);
        BARM; CLUST(0); BARM;
        BF_READ(b, 0, 1);
        if (more) { STAGE_B2(nb, tl + 1, 0); VMW4; } else { VMW0; }
        BARM; CLUST(1); BARM;
        AF_READ(b, 1); BF_READ(b, 1, 0);
        if (more) STAGE_A2(nb, tl + 1, 1);
        BARM; CLUST(0); BARM;
        BF_READ(b, 1, 1);
        if (more) { STAGE_B2(nb, tl + 1, 1); VMW4; }
        BARM; CLUST(1); BARM;
    }
    #undef STAGE_A2
    #undef STAGE_B2

#pragma unroll
    for (int ni = 0; ni < 4; ni++) {
        int cp = pn * 256 + wc * 64 + ni * 16 + fr;
#pragma unroll
        for (int mi = 0; mi < 8; mi++) {
#pragma unroll
            for (int j = 0; j < 4; j++) {
                int rl = wr * 128 + mi * 16 + kc * 4 + j;
                if (m0 + rl >= cnt) continue;
                float v = (acc[mi][ni][j] + bb3[ni]) * rowwt[rl];
                P[(size_t)(bex + m0 + rl) * 512 + cp] = v;
            }
        }
    }
}

// out[tok][colbase + c] = P[inv[2t]][c] + P[inv[2t+1]][c]
__global__ __launch_bounds__(256) void combine_kernel(
    const float* __restrict__ P, const int* __restrict__ inv,
    float* __restrict__ out, int colbase)
{
    int gid = blockIdx.x * 256 + threadIdx.x;
    int tok = gid >> 7;
    int c4 = (gid & 127) * 4;
    const float4 a = *(const float4*)(P + (size_t)inv[tok * 2] * 512 + c4);
    const float4 b = *(const float4*)(P + (size_t)inv[tok * 2 + 1] * 512 + c4);
    float4 r = make_float4(a.x + b.x, a.y + b.y, a.z + b.z, a.w + b.w);
    *(float4*)(out + (size_t)tok * DIM + colbase + c4) = r;
}

extern "C" void kernel_launch(void* const* d_in, const int* in_sizes, int n_in,
                              void* d_out, int out_size, void* d_ws, size_t ws_size,
                              hipStream_t stream) {
    (void)in_sizes; (void)n_in; (void)out_size; (void)ws_size;
    const float* x      = (const float*)d_in[0];
    const float* gate_w = (const float*)d_in[1];
    const float* gate_b = (const float*)d_in[2];
    const float* w1     = (const float*)d_in[3];
    const float* b1     = (const float*)d_in[4];
    const float* w2     = (const float*)d_in[5];
    const float* b2     = (const float*)d_in[6];
    const float* w3     = (const float*)d_in[7];
    const float* b3     = (const float*)d_in[8];
    float* out = (float*)d_out;

    char* ws = (char*)d_ws;
    float* usage      = (float*)ws;                               // @0, 32 B
    int*   counts     = (int*)(ws + 32);                          // @32, 32 B
    int*   base_exact = (int*)(ws + 64);                          // @64, 32 B
    int*   ntiles     = (int*)(ws + 96);                          // @96, 16 B
    int*   tmap_e     = (int*)(ws + 128);                         // 512 B
    int*   tmap_m0    = (int*)(ws + 640);                         // 512 B
    int*   lists      = (int*)(ws + 4096);                        // 256 KB
    float* wts        = (float*)(ws + 4096 + (size_t)NE * N_TOK * 4);   // 256 KB
    int*   inv        = (int*)(ws + 4096 + (size_t)2 * NE * N_TOK * 4); // 64 KB
    int*   sel        = (int*)(ws + 4096 + 576 * 1024);           // 32 KB
    float2* wpair     = (float2*)(ws + 4096 + 608 * 1024);        // 64 KB
    float* usage_part = (float*)(ws + 4096 + 672 * 1024);         // 64 KB
    us* Hsw   = (us*)(ws + (1ull  << 20));                        // @1 MiB, 64 MiB
    us* W12sw = (us*)(ws + (65ull << 20));                        // @65 MiB, 64 MiB (ffn1 phase)
    us* W3sw  = W12sw;                                            // @65 MiB, 32 MiB (ffn2 phase)
    float* P  = (float*)(ws + (97ull << 20));                     // @97 MiB, 32 MiB (ffn2 phase)
    us* Xg    = (us*)d_out;                                       // 32 MiB, routing-order X

    gate_compute<<<N_TOK / 4, 256, 0, stream>>>(x, gate_w, gate_b, sel, wpair, usage_part);
    scan_kernel<<<NE, 256, 0, stream>>>(sel, wpair, counts, lists, wts);
    usage_reduce<<<1, 256, 0, stream>>>(usage_part, usage);
    prefix_kernel<<<1, 64, 0, stream>>>(counts, base_exact, ntiles, tmap_e, tmap_m0);
    {
        dim3 gI(N_TOK / 256, NE);
        inv_kernel<<<gI, 256, 0, stream>>>(counts, lists, base_exact, inv);
    }
    xgather_kernel<<<N_TOK * 2 / 128, 256, 0, stream>>>(x, counts, lists, base_exact, Xg);

    dim3 gW12(16, NB1, NE);
    wswz12_kernel<<<gW12, 256, 0, stream>>>(w1, w2, W12sw);

    ffn1_mfma_kernel<<<NB1 * MAXT, 512, 0, stream>>>(Xg, W12sw, b1, b2, counts, base_exact,
                                                     ntiles, tmap_e, tmap_m0, Hsw);

    loss_kernel<<<1, 64, 0, stream>>>(usage, out + (size_t)N_TOK * DIM);

    dim3 gW3(32, NB2, NE);
    wswz3_kernel<<<gW3, 256, 0, stream>>>(w3, W3sw);

    ffn2_mfma_kernel<<<2 * MAXT, 512, 0, stream>>>(Hsw, W3sw, b3, counts, base_exact,
                                                   ntiles, tmap_e, tmap_m0, wts, P, 0);
    combine_kernel<<<N_TOK * 128 / 256, 256, 0, stream>>>(P, inv, out, 0);
    ffn2_mfma_kernel<<<2 * MAXT, 512, 0, stream>>>(Hsw, W3sw, b3, counts, base_exact,
                                                   ntiles, tmap_e, tmap_m0, wts, P, 2);
    combine_kernel<<<N_TOK * 128 / 256, 256, 0, stream>>>(P, inv, out, 512);
}

// Round 15
// 495.769 us; speedup vs baseline: 1.4467x; 1.0007x over previous
//
#include <hip/hip_runtime.h>
#include <hip/hip_bf16.h>
#include <math.h>

#define N_TOK 8192
#define DIM   1024
#define HID   2048
#define NE    8
#define NT1   16     // DIM/64 K-tiles (ffn1)
#define NT2   32     // HID/64 K-tiles (ffn2)
#define NB1   16     // HID/128 panels (ffn1)
#define NB2   4      // DIM/256 panels (ffn2)
#define MAXT  72     // max (e,m0) tiles
#define PANEL1_SH ((size_t)(128 * 256 * 8))   // shorts per ffn1 [W1|W2] panel (512KB)
#define PANEL3_SH ((size_t)(256 * 256 * 8))   // shorts per w3 256-col panel (1MB)
#define XBLK_SH   ((size_t)(128 * 128 * 8))   // shorts per 128-row Xg block (256KB)
#define HBLK_SH   ((size_t)(256 * 128 * 8))   // shorts per 128-row Hsw block (512KB)

typedef __attribute__((ext_vector_type(8))) short short8;
typedef __attribute__((ext_vector_type(4))) float f32x4;
typedef unsigned short us;

__device__ __forceinline__ us f2bf(float f) {
    unsigned int u = __builtin_bit_cast(unsigned int, f);
    unsigned int r = (u + 0x7fffu + ((u >> 16) & 1u)) >> 16;   // RNE
    return (us)r;
}

__device__ __forceinline__ void gl_lds16(const us* g, us* l) {
    __builtin_amdgcn_global_load_lds(
        (const __attribute__((address_space(1))) void*)g,
        (__attribute__((address_space(3))) void*)l, 16, 0, 0);
}

#define VMW4 asm volatile("s_waitcnt vmcnt(4)" ::: "memory")
#define VMW0 asm volatile("s_waitcnt vmcnt(0)" ::: "memory")
#define BARM asm volatile("s_barrier" ::: "memory")
#define PRIO1 __builtin_amdgcn_s_setprio(1)
#define PRIO0 __builtin_amdgcn_s_setprio(0)

// ---------------- gating phase A: logits/softmax/top2, NO global atomics ----------------
__global__ __launch_bounds__(256) void gate_compute(
    const float* __restrict__ x, const float* __restrict__ gw, const float* __restrict__ gb,
    int* __restrict__ sel, float2* __restrict__ wpair, float* __restrict__ usage_part)
{
    const int lane = threadIdx.x & 63;
    const int tok = blockIdx.x * 4 + (threadIdx.x >> 6);

    __shared__ float su[NE];
    if (threadIdx.x < NE) su[threadIdx.x] = 0.f;
    __syncthreads();

    float acc[NE];
#pragma unroll
    for (int e = 0; e < NE; e++) acc[e] = 0.f;

    const float* xr = x + (size_t)tok * DIM;
    for (int d = lane; d < DIM; d += 64) {
        float xv = xr[d];
        const float4* g4 = (const float4*)(gw + (size_t)d * NE);
        float4 ga = g4[0], gc = g4[1];
        acc[0] = fmaf(xv, ga.x, acc[0]);
        acc[1] = fmaf(xv, ga.y, acc[1]);
        acc[2] = fmaf(xv, ga.z, acc[2]);
        acc[3] = fmaf(xv, ga.w, acc[3]);
        acc[4] = fmaf(xv, gc.x, acc[4]);
        acc[5] = fmaf(xv, gc.y, acc[5]);
        acc[6] = fmaf(xv, gc.z, acc[6]);
        acc[7] = fmaf(xv, gc.w, acc[7]);
    }
#pragma unroll
    for (int e = 0; e < NE; e++) {
#pragma unroll
        for (int off = 32; off > 0; off >>= 1)
            acc[e] += __shfl_xor(acc[e], off);
    }

    if (lane == 0) {
        float lg[NE], p[NE];
        float mx = -1e30f;
#pragma unroll
        for (int e = 0; e < NE; e++) { lg[e] = acc[e] + gb[e]; mx = fmaxf(mx, lg[e]); }
        float s = 0.f;
#pragma unroll
        for (int e = 0; e < NE; e++) { p[e] = __expf(lg[e] - mx); s += p[e]; }
        float inv = 1.f / s;
#pragma unroll
        for (int e = 0; e < NE; e++) p[e] *= inv;
#pragma unroll
        for (int e = 0; e < NE; e++) atomicAdd(&su[e], p[e]);   // LDS atomic only

        int e1 = 0; float v1 = p[0];
#pragma unroll
        for (int e = 1; e < NE; e++) if (p[e] > v1) { v1 = p[e]; e1 = e; }
        int e2 = -1; float v2 = -1e30f;
#pragma unroll
        for (int e = 0; e < NE; e++) if (e != e1 && p[e] > v2) { v2 = p[e]; e2 = e; }

        sel[tok] = e1 | (e2 << 4);
        wpair[tok] = make_float2(v1, v2);
    }
    __syncthreads();
    if (threadIdx.x < NE) usage_part[blockIdx.x * NE + threadIdx.x] = su[threadIdx.x];
}

// ---------------- gating phase B: deterministic counting-sort, one block per expert ----------------
__global__ __launch_bounds__(256) void scan_kernel(
    const int* __restrict__ sel, const float2* __restrict__ wpair,
    int* __restrict__ counts, int* __restrict__ lists, float* __restrict__ wlist)
{
    const int e = blockIdx.x;
    const int t = threadIdx.x;
    const int base_tok = t * 32;

    unsigned selm = 0, km = 0;
#pragma unroll
    for (int i = 0; i < 32; i++) {
        int s = sel[base_tok + i];
        int e1 = s & 15, e2 = (s >> 4) & 15;
        if (e1 == e) selm |= (1u << i);
        else if (e2 == e) { selm |= (1u << i); km |= (1u << i); }
    }
    const int myc = __popc(selm);

    __shared__ int tot[256];
    tot[t] = myc;
    __syncthreads();
#pragma unroll
    for (int d = 1; d < 256; d <<= 1) {
        int v = (t >= d) ? tot[t - d] : 0;
        __syncthreads();
        tot[t] += v;
        __syncthreads();
    }
    int pos = tot[t] - myc;          // exclusive prefix
    if (t == 255) counts[e] = tot[255];

    for (int i = 0; i < 32; i++) {
        if (selm & (1u << i)) {
            int tok = base_tok + i;
            int k = (km >> i) & 1;
            lists[e * N_TOK + pos] = tok * 2 + k;
            float2 wp = wpair[tok];
            wlist[e * N_TOK + pos] = k ? wp.y : wp.x;
            pos++;
        }
    }
}

// usage[e] = deterministic tree-sum of 2048 per-block partials
__global__ __launch_bounds__(256) void usage_reduce(
    const float* __restrict__ part, float* __restrict__ usage)
{
    const int t = threadIdx.x;
    const int e = t & 7, chunk = t >> 3;
    float s = 0.f;
    for (int b = chunk; b < 2048; b += 32) s += part[b * NE + e];
    __shared__ float red[256];
    red[t] = s;
    __syncthreads();
#pragma unroll
    for (int step = 128; step >= 8; step >>= 1) {
        if (t < step) red[t] += red[t + step];
        __syncthreads();
    }
    if (t < NE) usage[t] = red[t];
}

__global__ void loss_kernel(const float* __restrict__ usage, float* __restrict__ out_loss)
{
    if (threadIdx.x == 0) {
        float l = 0.f;
        for (int e = 0; e < NE; e++) {
            float u = usage[e] / (float)N_TOK;
            l += u * logf(u + 1e-9f);
        }
        *out_loss = l;
    }
}

// exact prefix + dense (e, m0) tile worklist
__global__ void prefix_kernel(const int* __restrict__ counts,
                              int* __restrict__ base_exact, int* __restrict__ ntiles,
                              int* __restrict__ tmap_e, int* __restrict__ tmap_m0)
{
    if (threadIdx.x == 0) {
        int bx = 0, nt = 0;
        for (int e = 0; e < NE; e++) {
            base_exact[e] = bx;
            for (int m0 = 0; m0 < counts[e]; m0 += 256) {
                tmap_e[nt] = e; tmap_m0[nt] = m0; nt++;
            }
            bx += counts[e];
        }
        ntiles[0] = nt;
    }
}

// inv[rid] = global list position of routing entry rid
__global__ __launch_bounds__(256) void inv_kernel(
    const int* __restrict__ counts, const int* __restrict__ lists,
    const int* __restrict__ base_exact, int* __restrict__ inv)
{
    const int e = blockIdx.y;
    const int idx = blockIdx.x * 256 + threadIdx.x;
    if (idx < counts[e]) inv[lists[e * N_TOK + idx]] = base_exact[e] + idx;
}

// ---------------- X pre-gather: x -> Xg (bf16, routing order, chunk-tiled) ----------------
__global__ __launch_bounds__(256) void xgather_kernel(
    const float* __restrict__ x,
    const int* __restrict__ counts, const int* __restrict__ lists,
    const int* __restrict__ base_exact,
    us* __restrict__ Xg)
{
    __shared__ int toks[128];
    __shared__ int bexs[NE], cnts[NE];
    const int t = threadIdx.x;
    if (t < NE) { bexs[t] = base_exact[t]; cnts[t] = counts[t]; }
    __syncthreads();
    if (t < 128) {
        int gpos = blockIdx.x * 128 + t;
        int e = 0;
#pragma unroll
        for (int k = 1; k < NE; k++) if (gpos >= bexs[k]) e = k;
        int idx = gpos - bexs[e];
        int tok = (idx < cnts[e]) ? (lists[e * N_TOK + idx] >> 1) : 0;
        toks[t] = tok;
    }
    __syncthreads();

    us* op = Xg + (size_t)blockIdx.x * XBLK_SH;
    const int rr = t & 127;
    const int ch = t >> 7;
    const int tok = toks[rr];
#pragma unroll
    for (int it = 0; it < 64; it++) {
        int c = it * 2 + ch;
        const float4* src = (const float4*)(x + (size_t)tok * DIM + c * 8);
        float4 a = src[0], b = src[1];
        short8 v;
        v[0] = (short)f2bf(a.x); v[1] = (short)f2bf(a.y);
        v[2] = (short)f2bf(a.z); v[3] = (short)f2bf(a.w);
        v[4] = (short)f2bf(b.x); v[5] = (short)f2bf(b.y);
        v[6] = (short)f2bf(b.z); v[7] = (short)f2bf(b.w);
        *(short8*)(op + (size_t)(c * 128 + rr) * 8) = v;
    }
}

// ---------------- w1,w2 -> [e][nbx16][g128][row256][8], rows = [W1 128 | W2 128] ----------------
__global__ __launch_bounds__(256) void wswz12_kernel(
    const float* __restrict__ w1, const float* __restrict__ w2, us* __restrict__ out)
{
    const int e = blockIdx.z, nbx = blockIdx.y, gs = blockIdx.x;
    us* op = out + ((size_t)e * NB1 + nbx) * PANEL1_SH + (size_t)gs * 8 * 256 * 8;
    const float* w1e = w1 + (size_t)e * DIM * HID;
    const float* w2e = w2 + (size_t)e * DIM * HID;
    const int t = threadIdx.x;
#pragma unroll
    for (int it = 0; it < 8; it++) {
        int idx = it * 256 + t;
        int g = idx >> 8, row = idx & 255;
        int col = nbx * 128 + (row & 127);
        const float* src = (row < 128 ? w1e : w2e) + (size_t)((gs * 8 + g) * 8) * HID + col;
        short8 v;
#pragma unroll
        for (int s = 0; s < 8; s++) v[s] = (short)f2bf(src[(size_t)s * HID]);
        *(short8*)(op + (size_t)idx * 8) = v;
    }
}

// ---------------- w3 -> [e][nbx4][g256][row256][8] ----------------
__global__ __launch_bounds__(256) void wswz3_kernel(
    const float* __restrict__ w3, us* __restrict__ out)
{
    const int e = blockIdx.z, nbx = blockIdx.y, gs = blockIdx.x;
    us* op = out + ((size_t)e * NB2 + nbx) * PANEL3_SH + (size_t)gs * 8 * 256 * 8;
    const float* w3e = w3 + (size_t)e * HID * DIM;
    const int t = threadIdx.x;
#pragma unroll
    for (int it = 0; it < 8; it++) {
        int idx = it * 256 + t;
        int g = idx >> 8, row = idx & 255;
        int col = nbx * 256 + row;
        const float* src = w3e + (size_t)((gs * 8 + g) * 8) * DIM + col;
        short8 v;
#pragma unroll
        for (int s = 0; s < 8; s++) v[s] = (short)f2bf(src[(size_t)s * DIM]);
        *(short8*)(op + (size_t)idx * 8) = v;
    }
}

#define ABUF(b) ((us*)(SM + (b)*32768))
#define BBUF(b) ((us*)(SM + 65536 + (b)*32768))

#define AF_READ(b, h) do {                                               \
    _Pragma("unroll")                                                    \
    for (int mi = 0; mi < 8; mi++)                                       \
        af[mi] = *(const short8*)(ABUF(b) + ((h)*1024 + kc*256 + Mw + mi*16 + fr)*8); \
} while (0)
// all 4 column fragments of the 64-col wave panel for k-half h
#define BF_READ4(b, h) do {                                              \
    _Pragma("unroll")                                                    \
    for (int j = 0; j < 4; j++)                                          \
        bfv[j] = *(const short8*)(BBUF(b) + ((h)*1024 + kc*256 + Nw + j*16 + fr)*8); \
} while (0)
// 32-MFMA cluster: full wave sub-tile for one k-half
#define CLUST4 do {                                                      \
    PRIO1;                                                               \
    _Pragma("unroll")                                                    \
    for (int j = 0; j < 4; j++) {                                        \
        _Pragma("unroll")                                                \
        for (int mi = 0; mi < 8; mi++)                                   \
            acc[mi][j] = __builtin_amdgcn_mfma_f32_16x16x32_bf16(        \
                af[mi], bfv[j], acc[mi][j], 0, 0, 0);                    \
    }                                                                    \
    PRIO0;                                                               \
} while (0)

// ---------------- pass A: Xg @ [W1|W2] -> swiglu -> Hsw ----------------
// 2-phase K-tile loop (one phase per 32-k half), counted vmcnt, XCD-aware panels.
__global__ __launch_bounds__(512, 2) void ffn1_mfma_kernel(
    const us* __restrict__ Xg, const us* __restrict__ W12sw,
    const float* __restrict__ b1, const float* __restrict__ b2,
    const int* __restrict__ counts, const int* __restrict__ base_exact,
    const int* __restrict__ ntiles, const int* __restrict__ tmap_e, const int* __restrict__ tmap_m0,
    us* __restrict__ Hsw)
{
    const int hw = blockIdx.x;
    const int ix = hw >> 3;
    const int nbx = ((hw & 7) << 1) | (ix & 1);      // XCD*2 + sub
    const int by  = ix >> 1;
    if (by >= ntiles[0]) return;
    const int e  = tmap_e[by];
    const int m0 = tmap_m0[by];
    const int cnt = counts[e];
    const int bex = base_exact[e];

    __shared__ __align__(16) unsigned char SM[132096];

    const int t = threadIdx.x;
    const int lane = t & 63, wv = t >> 6;
    const int wr = wv >> 2, wc = wv & 3;
    const int Mw = wr * 128, Nw = wc * 64;
    const int fr = lane & 15, kc = lane >> 4;

    float bb[4];
    {
        const float* bsrc = (wc < 2) ? b1 : b2;
#pragma unroll
        for (int ni = 0; ni < 4; ni++)
            bb[ni] = bsrc[e * HID + nbx * 128 + (wc & 1) * 64 + ni * 16 + fr];
    }
    __syncthreads();

    const int c0 = wv * 128 + lane;
    const int c1 = c0 + 64;
    const int RA0 = min(bex + m0 + (c0 & 255), N_TOK * 2 - 1);
    const int RA1 = min(bex + m0 + (c1 & 255), N_TOK * 2 - 1);
    const us* ApA = Xg + (size_t)(RA0 >> 7) * XBLK_SH + (size_t)(c0 >> 8) * 1024 + (RA0 & 127) * 8;
    const us* ApB = Xg + (size_t)(RA1 >> 7) * XBLK_SH + (size_t)(c1 >> 8) * 1024 + (RA1 & 127) * 8;
    const us* Wp = W12sw + ((size_t)e * NB1 + nbx) * PANEL1_SH;
    const int dbase = wv * 128 * 8;

    f32x4 acc[8][4];
    const f32x4 fz = {0.f, 0.f, 0.f, 0.f};
#pragma unroll
    for (int i = 0; i < 8; i++)
#pragma unroll
        for (int j = 0; j < 4; j++) acc[i][j] = fz;

    #define STAGE_A(b, tile, h) do {                                             \
        gl_lds16(ApA + (size_t)((tile)*8 + (h)*4) * 1024, ABUF(b) + ((h)*1024)*8 + dbase); \
        gl_lds16(ApB + (size_t)((tile)*8 + (h)*4) * 1024, ABUF(b) + ((h)*1024 + 64)*8 + dbase); \
    } while (0)
    #define STAGE_B(b, tile, h) do {                                             \
        const us* s_ = Wp + ((size_t)(tile)*2048 + (h)*1024) * 8;                \
        gl_lds16(s_ + (size_t)c0 * 8, BBUF(b) + ((h)*1024)*8 + dbase);           \
        gl_lds16(s_ + (size_t)c1 * 8, BBUF(b) + ((h)*1024 + 64)*8 + dbase);      \
    } while (0)

    short8 af[8], bfv[4];

    STAGE_A(0, 0, 0); STAGE_B(0, 0, 0); STAGE_A(0, 0, 1); STAGE_B(0, 0, 1);
    VMW4; BARM;

    for (int tl = 0; tl < NT1; ++tl) {
        const int b = tl & 1, nb = b ^ 1;
        const bool more = (tl + 1 < NT1);
        // PH0: k-half 0
        AF_READ(b, 0); BF_READ4(b, 0);
        if (more) { STAGE_A(nb, tl + 1, 0); STAGE_B(nb, tl + 1, 0); VMW4; } else { VMW0; }
        BARM; CLUST4; BARM;
        // PH1: k-half 1
        AF_READ(b, 1); BF_READ4(b, 1);
        if (more) { STAGE_A(nb, tl + 1, 1); STAGE_B(nb, tl + 1, 1); VMW4; }
        BARM; CLUST4; BARM;
    }
    #undef STAGE_A
    #undef STAGE_B

    // ---- SwiGLU epilogue via LDS gate exchange ----
    float* G = (float*)SM;
    if (wc >= 2) {
        const int cp = wc - 2;
#pragma unroll
        for (int ni = 0; ni < 4; ni++) {
            int c2 = cp * 64 + ni * 16 + fr;
#pragma unroll
            for (int mi = 0; mi < 8; mi++) {
#pragma unroll
                for (int j = 0; j < 4; j++) {
                    int m = mi * 16 + kc * 4 + j;
                    float g = 1.f / (1.f + __expf(-(acc[mi][ni][j] + bb[ni])));
                    G[(wr * 128 + c2) * 129 + m] = g;
                }
            }
        }
    }
    __syncthreads();
    if (wc < 2) {
#pragma unroll
        for (int ni = 0; ni < 4; ni++) {
            int c2 = wc * 64 + ni * 16 + fr;
            int ch = nbx * 128 + c2;
            size_t cb = (size_t)(ch >> 3) * 128 * 8 + (ch & 7);
#pragma unroll
            for (int mi = 0; mi < 8; mi++) {
#pragma unroll
                for (int j = 0; j < 4; j++) {
                    int m = mi * 16 + kc * 4 + j;
                    int rl = wr * 128 + m;
                    if (m0 + rl >= cnt) continue;
                    float h = (acc[mi][ni][j] + bb[ni]) * G[(wr * 128 + c2) * 129 + m];
                    int R = bex + m0 + rl;
                    Hsw[(size_t)(R >> 7) * HBLK_SH + cb + (size_t)(R & 127) * 8] = f2bf(h);
                }
            }
        }
    }
}

// ---------------- pass B: Hsw @ w3 -> f32 partials P ----------------
// 2-phase K-tile loop; XCD-aware panel split.
__global__ __launch_bounds__(512, 2) void ffn2_mfma_kernel(
    const us* __restrict__ Hsw, const us* __restrict__ W3sw, const float* __restrict__ b3,
    const int* __restrict__ counts, const int* __restrict__ base_exact,
    const int* __restrict__ ntiles, const int* __restrict__ tmap_e, const int* __restrict__ tmap_m0,
    const float* __restrict__ wts,
    float* __restrict__ P, int pan0)
{
    const int hw = blockIdx.x;
    const int xcd = hw & 7;
    const int ix = hw >> 3;
    const int pn = xcd >> 2;
    const int by = (ix << 2) | (xcd & 3);
    if (by >= ntiles[0]) return;
    const int e  = tmap_e[by];
    const int m0 = tmap_m0[by];
    const int cnt = counts[e];
    const int bex = base_exact[e];
    const int nbx = pan0 + pn;

    __shared__ __align__(16) unsigned char SM[132096];
    float* rowwt = (float*)(SM + 131072);

    const int t = threadIdx.x;
    if (t < 256) {
        int idx = m0 + t;
        rowwt[t] = (idx < cnt) ? wts[e * N_TOK + idx] : 0.f;
    }

    const int lane = t & 63, wv = t >> 6;
    const int wr = wv >> 2, wc = wv & 3;
    const int Mw = wr * 128, Nw = wc * 64;
    const int fr = lane & 15, kc = lane >> 4;

    float bb3[4];
#pragma unroll
    for (int ni = 0; ni < 4; ni++)
        bb3[ni] = b3[e * DIM + nbx * 256 + wc * 64 + ni * 16 + fr];
    __syncthreads();

    const int c0 = wv * 128 + lane;
    const int c1 = c0 + 64;
    const int RA0 = min(bex + m0 + (c0 & 255), N_TOK * 2 - 1);
    const int RA1 = min(bex + m0 + (c1 & 255), N_TOK * 2 - 1);
    const us* HpA = Hsw + (size_t)(RA0 >> 7) * HBLK_SH + (size_t)(c0 >> 8) * 1024 + (RA0 & 127) * 8;
    const us* HpB = Hsw + (size_t)(RA1 >> 7) * HBLK_SH + (size_t)(c1 >> 8) * 1024 + (RA1 & 127) * 8;
    const us* Wp = W3sw + ((size_t)e * NB2 + nbx) * PANEL3_SH;
    const int dbase = wv * 128 * 8;

    f32x4 acc[8][4];
    const f32x4 fz = {0.f, 0.f, 0.f, 0.f};
#pragma unroll
    for (int i = 0; i < 8; i++)
#pragma unroll
        for (int j = 0; j < 4; j++) acc[i][j] = fz;

    #define STAGE_A2(b, tile, h) do {                                            \
        gl_lds16(HpA + (size_t)((tile)*8 + (h)*4) * 1024, ABUF(b) + ((h)*1024)*8 + dbase); \
        gl_lds16(HpB + (size_t)((tile)*8 + (h)*4) * 1024, ABUF(b) + ((h)*1024 + 64)*8 + dbase); \
    } while (0)
    #define STAGE_B2(b, tile, h) do {                                            \
        const us* s_ = Wp + ((size_t)(tile)*2048 + (h)*1024) * 8;                \
        gl_lds16(s_ + (size_t)c0 * 8, BBUF(b) + ((h)*1024)*8 + dbase);           \
        gl_lds16(s_ + (size_t)c1 * 8, BBUF(b) + ((h)*1024 + 64)*8 + dbase);      \
    } while (0)

    short8 af[8], bfv[4];

    STAGE_A2(0, 0, 0); STAGE_B2(0, 0, 0); STAGE_A2(0, 0, 1); STAGE_B2(0, 0, 1);
    VMW4; BARM;

    for (int tl = 0; tl < NT2; ++tl) {
        const int b = tl & 1, nb = b ^ 1;
        const bool more = (tl + 1 < NT2);
        AF_READ(b, 0); BF_READ4(b, 0);
        if (more) { STAGE_A2(nb, tl + 1, 0); STAGE_B2(nb, tl + 1, 0); VMW4; } else { VMW0; }
        BARM; CLUST4; BARM;
        AF_READ(b, 1); BF_READ4(b, 1);
        if (more) { STAGE_A2(nb, tl + 1, 1); STAGE_B2(nb, tl + 1, 1); VMW4; }
        BARM; CLUST4; BARM;
    }
    #undef STAGE_A2
    #undef STAGE_B2

#pragma unroll
    for (int ni = 0; ni < 4; ni++) {
        int cp = pn * 256 + wc * 64 + ni * 16 + fr;
#pragma unroll
        for (int mi = 0; mi < 8; mi++) {
#pragma unroll
            for (int j = 0; j < 4; j++) {
                int rl = wr * 128 + mi * 16 + kc * 4 + j;
                if (m0 + rl >= cnt) continue;
                float v = (acc[mi][ni][j] + bb3[ni]) * rowwt[rl];
                P[(size_t)(bex + m0 + rl) * 512 + cp] = v;
            }
        }
    }
}

// out[tok][colbase + c] = P[inv[2t]][c] + P[inv[2t+1]][c]
__global__ __launch_bounds__(256) void combine_kernel(
    const float* __restrict__ P, const int* __restrict__ inv,
    float* __restrict__ out, int colbase)
{
    int gid = blockIdx.x * 256 + threadIdx.x;
    int tok = gid >> 7;
    int c4 = (gid & 127) * 4;
    const float4 a = *(const float4*)(P + (size_t)inv[tok * 2] * 512 + c4);
    const float4 b = *(const float4*)(P + (size_t)inv[tok * 2 + 1] * 512 + c4);
    float4 r = make_float4(a.x + b.x, a.y + b.y, a.z + b.z, a.w + b.w);
    *(float4*)(out + (size_t)tok * DIM + colbase + c4) = r;
}

extern "C" void kernel_launch(void* const* d_in, const int* in_sizes, int n_in,
                              void* d_out, int out_size, void* d_ws, size_t ws_size,
                              hipStream_t stream) {
    (void)in_sizes; (void)n_in; (void)out_size; (void)ws_size;
    const float* x      = (const float*)d_in[0];
    const float* gate_w = (const float*)d_in[1];
    const float* gate_b = (const float*)d_in[2];
    const float* w1     = (const float*)d_in[3];
    const float* b1     = (const float*)d_in[4];
    const float* w2     = (const float*)d_in[5];
    const float* b2     = (const float*)d_in[6];
    const float* w3     = (const float*)d_in[7];
    const float* b3     = (const float*)d_in[8];
    float* out = (float*)d_out;

    char* ws = (char*)d_ws;
    float* usage      = (float*)ws;                               // @0, 32 B
    int*   counts     = (int*)(ws + 32);                          // @32, 32 B
    int*   base_exact = (int*)(ws + 64);                          // @64, 32 B
    int*   ntiles     = (int*)(ws + 96);                          // @96, 16 B
    int*   tmap_e     = (int*)(ws + 128);                         // 512 B
    int*   tmap_m0    = (int*)(ws + 640);                         // 512 B
    int*   lists      = (int*)(ws + 4096);                        // 256 KB
    float* wts        = (float*)(ws + 4096 + (size_t)NE * N_TOK * 4);   // 256 KB
    int*   inv        = (int*)(ws + 4096 + (size_t)2 * NE * N_TOK * 4); // 64 KB
    int*   sel        = (int*)(ws + 4096 + 576 * 1024);           // 32 KB
    float2* wpair     = (float2*)(ws + 4096 + 608 * 1024);        // 64 KB
    float* usage_part = (float*)(ws + 4096 + 672 * 1024);         // 64 KB
    us* Hsw   = (us*)(ws + (1ull  << 20));                        // @1 MiB, 64 MiB
    us* W12sw = (us*)(ws + (65ull << 20));                        // @65 MiB, 64 MiB (ffn1 phase)
    us* W3sw  = W12sw;                                            // @65 MiB, 32 MiB (ffn2 phase)
    float* P  = (float*)(ws + (97ull << 20));                     // @97 MiB, 32 MiB (ffn2 phase)
    us* Xg    = (us*)d_out;                                       // 32 MiB, routing-order X

    gate_compute<<<N_TOK / 4, 256, 0, stream>>>(x, gate_w, gate_b, sel, wpair, usage_part);
    scan_kernel<<<NE, 256, 0, stream>>>(sel, wpair, counts, lists, wts);
    usage_reduce<<<1, 256, 0, stream>>>(usage_part, usage);
    prefix_kernel<<<1, 64, 0, stream>>>(counts, base_exact, ntiles, tmap_e, tmap_m0);
    {
        dim3 gI(N_TOK / 256, NE);
        inv_kernel<<<gI, 256, 0, stream>>>(counts, lists, base_exact, inv);
    }
    xgather_kernel<<<N_TOK * 2 / 128, 256, 0, stream>>>(x, counts, lists, base_exact, Xg);

    dim3 gW12(16, NB1, NE);
    wswz12_kernel<<<gW12, 256, 0, stream>>>(w1, w2, W12sw);

    ffn1_mfma_kernel<<<NB1 * MAXT, 512, 0, stream>>>(Xg, W12sw, b1, b2, counts, base_exact,
                                                     ntiles, tmap_e, tmap_m0, Hsw);

    loss_kernel<<<1, 64, 0, stream>>>(usage, out + (size_t)N_TOK * DIM);

    dim3 gW3(32, NB2, NE);
    wswz3_kernel<<<gW3, 256, 0, stream>>>(w3, W3sw);

    ffn2_mfma_kernel<<<2 * MAXT, 512, 0, stream>>>(Hsw, W3sw, b3, counts, base_exact,
                                                   ntiles, tmap_e, tmap_m0, wts, P, 0);
    combine_kernel<<<N_TOK * 128 / 256, 256, 0, stream>>>(P, inv, out, 0);
    ffn2_mfma_kernel<<<2 * MAXT, 512, 0, stream>>>(Hsw, W3sw, b3, counts, base_exact,
                                                   ntiles, tmap_e, tmap_m0, wts, P, 2);
    combine_kernel<<<N_TOK * 128 / 256, 256, 0, stream>>>(P, inv, out, 512);
}